// Round 3
// baseline (4886.314 us; speedup 1.0000x reference)
//
#include <hip/hip_runtime.h>
#include <math.h>

#define NROWS 65536
#define DDIM 2048
#define NEXP 64
#define TOPK 8

constexpr int BM = 128;        // rows per block
constexpr int BK = 32;         // k-chunk
constexpr int NTH = 256;
constexpr int NT = DDIM / BK;  // 64 k-tiles
constexpr int SX = 130;        // xs stride: stores 2-way (free), float2 reads conflict-free
constexpr int SW = 66;         // ws stride: stores 2-way, float2 reads broadcast+2-way
constexpr int CAP = 8192;      // flagged-row list capacity (expect ~500)
constexpr float THR = 6e-5f;   // ambiguity gap threshold (~40 sigma of fp32 dot error)

// ws layout (words): [0..63] psum, [64..127] freq, [128] zsum, [129] cnt(int), [130..] rows
__global__ __launch_bounds__(NTH, 4)
void gate_kernel(const float* __restrict__ x, const float* __restrict__ W,
                 float* __restrict__ out_idx, float* __restrict__ out_gate,
                 float* __restrict__ g_psum, float* __restrict__ g_freq,
                 float* __restrict__ g_zsum, int* __restrict__ g_cnt,
                 int* __restrict__ g_rows)
{
    __shared__ float xs[BK][SX];
    __shared__ float ws[BK][SW];
    __shared__ float psum_s[NEXP];
    __shared__ float fcnt_s[NEXP];

    const int tid = threadIdx.x;
    const int row0 = blockIdx.x * BM;
    const int tx = tid & 7;    // expert group: experts tx*8 .. tx*8+7
    const int ty = tid >> 3;   // row group:    rows    ty*4 .. ty*4+3
    const int lane = tid & 63;
    const int sr = tid >> 3, sc = tid & 7;  // staging coords

    if (tid < NEXP) { psum_s[tid] = 0.f; fcnt_s[tid] = 0.f; }

    float4 rx[4], rw[2];  // register prefetch buffers

    auto load_tile = [&](int k0) {
#pragma unroll
        for (int it = 0; it < 4; ++it)
            rx[it] = *reinterpret_cast<const float4*>(
                &x[(size_t)(row0 + sr + 32 * it) * DDIM + k0 + sc * 4]);
#pragma unroll
        for (int it = 0; it < 2; ++it)
            rw[it] = *reinterpret_cast<const float4*>(
                &W[(size_t)(sr + 32 * it) * DDIM + k0 + sc * 4]);
    };
    auto store_tile = [&]() {
#pragma unroll
        for (int it = 0; it < 4; ++it) {
            int r = sr + 32 * it;
            xs[sc * 4 + 0][r] = rx[it].x; xs[sc * 4 + 1][r] = rx[it].y;
            xs[sc * 4 + 2][r] = rx[it].z; xs[sc * 4 + 3][r] = rx[it].w;
        }
#pragma unroll
        for (int it = 0; it < 2; ++it) {
            int e = sr + 32 * it;
            ws[sc * 4 + 0][e] = rw[it].x; ws[sc * 4 + 1][e] = rw[it].y;
            ws[sc * 4 + 2][e] = rw[it].z; ws[sc * 4 + 3][e] = rw[it].w;
        }
    };

    float acc[4][8];
#pragma unroll
    for (int i = 0; i < 4; ++i)
#pragma unroll
        for (int e = 0; e < 8; ++e) acc[i][e] = 0.f;

    load_tile(0);
    store_tile();
    for (int t = 0; t < NT; ++t) {
        __syncthreads();                       // LDS tile t visible
        if (t + 1 < NT) load_tile((t + 1) * BK);  // prefetch next tile into regs
#pragma unroll
        for (int kk = 0; kk < BK; ++kk) {
            float a[4], b[8];
            *reinterpret_cast<float2*>(&a[0]) =
                *reinterpret_cast<const float2*>(&xs[kk][ty * 4]);
            *reinterpret_cast<float2*>(&a[2]) =
                *reinterpret_cast<const float2*>(&xs[kk][ty * 4 + 2]);
#pragma unroll
            for (int j = 0; j < 4; ++j)
                *reinterpret_cast<float2*>(&b[j * 2]) =
                    *reinterpret_cast<const float2*>(&ws[kk][tx * 8 + j * 2]);
#pragma unroll
            for (int i = 0; i < 4; ++i)
#pragma unroll
                for (int e = 0; e < 8; ++e)
                    acc[i][e] = fmaf(a[i], b[e], acc[i][e]);
        }
        __syncthreads();                       // all done reading tile t
        if (t + 1 < NT) store_tile();
    }

    // ---- epilogue: 8 lanes of a ty-group cooperate per row ----
    float zsq_acc = 0.f;
    float pcol[8];
#pragma unroll
    for (int e = 0; e < 8; ++e) pcol[e] = 0.f;

    for (int i = 0; i < 4; ++i) {
        float ld[8];
#pragma unroll
        for (int e = 0; e < 8; ++e) ld[e] = acc[i][e];

        float tv[9]; int ti[9];
#pragma unroll
        for (int p = 0; p < 9; ++p) {  // top-8 + rank-9 (for gap test)
            float bv = -3.4e38f; int bgi = 127;
#pragma unroll
            for (int e = 0; e < 8; ++e)
                if (ld[e] > bv) { bv = ld[e]; bgi = tx * 8 + e; }
#pragma unroll
            for (int m = 1; m < 8; m <<= 1) {
                float ov = __shfl_xor(bv, m, 8);
                int ogi = __shfl_xor(bgi, m, 8);
                if (ov > bv || (ov == bv && ogi < bgi)) { bv = ov; bgi = ogi; }
            }
            tv[p] = bv; ti[p] = bgi;
#pragma unroll
            for (int e = 0; e < 8; ++e)        // winner clears (static idx)
                if (bgi == tx * 8 + e) ld[e] = -3.4e38f;
        }

        const int row = row0 + ty * 4 + i;

        // ambiguity: any adjacent gap in top-9 below THR -> fp64 recheck
        float mg = 3.4e38f;
#pragma unroll
        for (int p = 0; p < 8; ++p) mg = fminf(mg, tv[p] - tv[p + 1]);
        if (tx == 0 && mg < THR) {
            int idx = atomicAdd(g_cnt, 1);
            if (idx < CAP) g_rows[idx] = row;
        }

        // full softmax probs (for psum)
        const float m0 = tv[0];
        float pe[8], ps = 0.f;
#pragma unroll
        for (int e = 0; e < 8; ++e) { pe[e] = expf(acc[i][e] - m0); ps += pe[e]; }
        float s = ps;
#pragma unroll
        for (int m = 1; m < 8; m <<= 1) s += __shfl_xor(s, m, 8);
        const float inv_s = 1.f / s;
#pragma unroll
        for (int e = 0; e < 8; ++e) pcol[e] += pe[e] * inv_s;

        if (tx == 0) {  // z-loss: logaddexp(lse, log(1e-5))^2
            float lsef = m0 + logf(s);
            const float lb = -11.512925464970229f;
            float mx = fmaxf(lsef, lb), mn = fminf(lsef, lb);
            float z = mx + log1pf(expf(mn - mx));
            zsq_acc += z * z;
        }

        // gates: lane tx handles rank tx (select chain, no runtime array index)
        float mytv = tv[0]; int myti = ti[0];
#pragma unroll
        for (int p = 1; p < 8; ++p)
            if (tx == p) { mytv = tv[p]; myti = ti[p]; }
        float ge = expf(mytv - m0);
        float gs = ge;
#pragma unroll
        for (int m = 1; m < 8; m <<= 1) gs += __shfl_xor(gs, m, 8);
        const size_t base = (size_t)row * TOPK;
        out_idx[base + tx] = (float)myti;
        out_gate[base + tx] = ge / gs;
        atomicAdd(&fcnt_s[myti], 1.f);
    }

    // z-loss wave reduction -> global
#pragma unroll
    for (int off = 32; off > 0; off >>= 1) zsq_acc += __shfl_down(zsq_acc, off, 64);
    if (lane == 0) atomicAdd(g_zsum, zsq_acc);

    // probs column sums -> shared -> global
#pragma unroll
    for (int e = 0; e < 8; ++e) atomicAdd(&psum_s[tx * 8 + e], pcol[e]);
    __syncthreads();
    if (tid < NEXP) {
        atomicAdd(&g_psum[tid], psum_s[tid]);
        atomicAdd(&g_freq[tid], fcnt_s[tid]);
    }
}

// fp64 recheck of flagged rows: one wave per row, exact ordering + gates.
__global__ __launch_bounds__(256)
void fixup_kernel(const float* __restrict__ x, const float* __restrict__ W,
                  float* __restrict__ out_idx, float* __restrict__ out_gate,
                  const int* __restrict__ g_cnt, const int* __restrict__ g_rows)
{
    const int n = min(*g_cnt, CAP);
    const int lane = threadIdx.x & 63;
    const int wid = (blockIdx.x * blockDim.x + threadIdx.x) >> 6;
    const int nw = (gridDim.x * blockDim.x) >> 6;

    for (int i = wid; i < n; i += nw) {
        const int row = g_rows[i];
        const float* xr = x + (size_t)row * DDIM;
        double xl[32];
#pragma unroll
        for (int t = 0; t < 32; ++t) xl[t] = (double)xr[lane + 64 * t];

        double lg = 0.0;  // expert `lane` logit
        for (int e = 0; e < NEXP; ++e) {
            const float* wr = W + (size_t)e * DDIM;
            double p = 0.0;
#pragma unroll
            for (int t = 0; t < 32; ++t)
                p = fma(xl[t], (double)wr[lane + 64 * t], p);
#pragma unroll
            for (int m = 1; m < 64; m <<= 1) p += __shfl_xor(p, m, 64);
            if (lane == e) lg = p;
        }

        double v = lg;
        double tv[8]; int ti[8];
#pragma unroll
        for (int p = 0; p < 8; ++p) {
            double bv = v; int bgi = lane;
#pragma unroll
            for (int m = 1; m < 64; m <<= 1) {
                double ov = __shfl_xor(bv, m, 64);
                int ogi = __shfl_xor(bgi, m, 64);
                if (ov > bv || (ov == bv && ogi < bgi)) { bv = ov; bgi = ogi; }
            }
            tv[p] = bv; ti[p] = bgi;
            if (lane == bgi) v = -HUGE_VAL;
        }

        const double m0 = tv[0];
        double gs = 0.0, ge[8];
#pragma unroll
        for (int j = 0; j < 8; ++j) { ge[j] = exp(tv[j] - m0); gs += ge[j]; }
        if (lane < 8) {
            double myge = ge[0]; int myti = ti[0];
#pragma unroll
            for (int j = 1; j < 8; ++j)
                if (lane == j) { myge = ge[j]; myti = ti[j]; }
            const size_t base = (size_t)row * TOPK;
            out_idx[base + lane] = (float)myti;
            out_gate[base + lane] = (float)(myge / gs);
        }
    }
}

__global__ void finalize_kernel(const float* __restrict__ g_psum,
                                const float* __restrict__ g_freq,
                                const float* __restrict__ g_zsum,
                                float* __restrict__ out_loss)
{
    if (threadIdx.x == 0) {
        float sp = 0.f, sf = 0.f;
        for (int e = 0; e < NEXP; ++e) { sp += g_psum[e]; sf += g_freq[e]; }
        sp = fmaxf(sp, 1e-12f);
        sf = fmaxf(sf, 1e-12f);
        float sw = 0.f;
        for (int e = 0; e < NEXP; ++e) sw += (g_psum[e] / sp) * (g_freq[e] / sf);
        out_loss[0] = (float)NEXP * sw + 0.1f * (g_zsum[0] / (float)NROWS);
    }
}

extern "C" void kernel_launch(void* const* d_in, const int* in_sizes, int n_in,
                              void* d_out, int out_size, void* d_ws, size_t ws_size,
                              hipStream_t stream)
{
    const float* x = (const float*)d_in[0];
    const float* W = (const float*)d_in[1];
    float* out = (float*)d_out;
    float* out_idx  = out;                            // [65536*8] indices as float
    float* out_gate = out + (size_t)NROWS * TOPK;     // [65536*8] gates
    float* out_loss = out + (size_t)2 * NROWS * TOPK; // [1] loss

    float* acc = (float*)d_ws;        // psum[64] | freq[64] | zsum[1]
    int* cnt  = (int*)d_ws + 129;
    int* rows = (int*)d_ws + 130;
    hipMemsetAsync(d_ws, 0, 130 * sizeof(float), stream);  // psum,freq,zsum,cnt

    gate_kernel<<<NROWS / BM, NTH, 0, stream>>>(
        x, W, out_idx, out_gate, acc, acc + NEXP, acc + 2 * NEXP, cnt, rows);
    fixup_kernel<<<128, 256, 0, stream>>>(x, W, out_idx, out_gate, cnt, rows);
    finalize_kernel<<<1, 64, 0, stream>>>(acc, acc + NEXP, acc + 2 * NEXP, out_loss);
}

// Round 4
// 2993.231 us; speedup vs baseline: 1.6325x; 1.6325x over previous
//
#include <hip/hip_runtime.h>
#include <math.h>

#define NROWS 65536
#define DDIM 2048
#define NEXP 64
#define TOPK 8

constexpr int BM = 128;        // rows per block
constexpr int BK = 32;         // k-chunk
constexpr int NTH = 256;
constexpr int NT = DDIM / BK;  // 64 k-tiles
constexpr int SX = 130;        // xs stride: stores 2-way (free), float2 reads conflict-free
constexpr int SW = 66;         // ws stride: stores 2-way, float2 reads broadcast+2-way
constexpr int CAP = 8192;      // flagged-row list capacity (expect ~500)
constexpr float THR = 6e-5f;   // ambiguity gap threshold (~40 sigma of fp32 dot error)

// ws layout (words): [0..63] psum, [64..127] freq, [128] zsum, [129] cnt(int), [130..] rows
// NOTE: launch_bounds min-waves=2 — at 4 the compiler caps VGPRs at 64 and
// spills acc+prefetch to scratch (round-3 post-mortem: 18 GB scratch traffic).
__global__ __launch_bounds__(NTH, 2)
void gate_kernel(const float* __restrict__ x, const float* __restrict__ W,
                 float* __restrict__ out_idx, float* __restrict__ out_gate,
                 float* __restrict__ g_psum, float* __restrict__ g_freq,
                 float* __restrict__ g_zsum, int* __restrict__ g_cnt,
                 int* __restrict__ g_rows)
{
    __shared__ float xs[BK][SX];
    __shared__ float ws[BK][SW];
    __shared__ float psum_s[NEXP];
    __shared__ float fcnt_s[NEXP];

    const int tid = threadIdx.x;
    const int row0 = blockIdx.x * BM;
    const int tx = tid & 7;    // expert group: experts tx*8 .. tx*8+7
    const int ty = tid >> 3;   // row group:    rows    ty*4 .. ty*4+3
    const int lane = tid & 63;
    const int sr = tid >> 3, sc = tid & 7;  // staging coords

    if (tid < NEXP) { psum_s[tid] = 0.f; fcnt_s[tid] = 0.f; }

    float4 rx[4], rw[2];  // register prefetch buffers

    auto load_tile = [&](int k0) {
#pragma unroll
        for (int it = 0; it < 4; ++it)
            rx[it] = *reinterpret_cast<const float4*>(
                &x[(size_t)(row0 + sr + 32 * it) * DDIM + k0 + sc * 4]);
#pragma unroll
        for (int it = 0; it < 2; ++it)
            rw[it] = *reinterpret_cast<const float4*>(
                &W[(size_t)(sr + 32 * it) * DDIM + k0 + sc * 4]);
    };
    auto store_tile = [&]() {
#pragma unroll
        for (int it = 0; it < 4; ++it) {
            int r = sr + 32 * it;
            xs[sc * 4 + 0][r] = rx[it].x; xs[sc * 4 + 1][r] = rx[it].y;
            xs[sc * 4 + 2][r] = rx[it].z; xs[sc * 4 + 3][r] = rx[it].w;
        }
#pragma unroll
        for (int it = 0; it < 2; ++it) {
            int e = sr + 32 * it;
            ws[sc * 4 + 0][e] = rw[it].x; ws[sc * 4 + 1][e] = rw[it].y;
            ws[sc * 4 + 2][e] = rw[it].z; ws[sc * 4 + 3][e] = rw[it].w;
        }
    };

    float acc[4][8];
#pragma unroll
    for (int i = 0; i < 4; ++i)
#pragma unroll
        for (int e = 0; e < 8; ++e) acc[i][e] = 0.f;

    load_tile(0);
    store_tile();
    for (int t = 0; t < NT; ++t) {
        __syncthreads();                       // LDS tile t visible
        if (t + 1 < NT) load_tile((t + 1) * BK);  // prefetch next tile into regs
#pragma unroll
        for (int kk = 0; kk < BK; ++kk) {
            float a[4], b[8];
            *reinterpret_cast<float2*>(&a[0]) =
                *reinterpret_cast<const float2*>(&xs[kk][ty * 4]);
            *reinterpret_cast<float2*>(&a[2]) =
                *reinterpret_cast<const float2*>(&xs[kk][ty * 4 + 2]);
#pragma unroll
            for (int j = 0; j < 4; ++j)
                *reinterpret_cast<float2*>(&b[j * 2]) =
                    *reinterpret_cast<const float2*>(&ws[kk][tx * 8 + j * 2]);
#pragma unroll
            for (int i = 0; i < 4; ++i)
#pragma unroll
                for (int e = 0; e < 8; ++e)
                    acc[i][e] = fmaf(a[i], b[e], acc[i][e]);
        }
        __syncthreads();                       // all done reading tile t
        if (t + 1 < NT) store_tile();
    }

    // ---- epilogue: 8 lanes of a ty-group cooperate per row ----
    float zsq_acc = 0.f;
    float pcol[8];
#pragma unroll
    for (int e = 0; e < 8; ++e) pcol[e] = 0.f;

    for (int i = 0; i < 4; ++i) {
        float ld[8];
#pragma unroll
        for (int e = 0; e < 8; ++e) ld[e] = acc[i][e];

        float tv[9]; int ti[9];
#pragma unroll
        for (int p = 0; p < 9; ++p) {  // top-8 + rank-9 (for gap test)
            float bv = -3.4e38f; int bgi = 127;
#pragma unroll
            for (int e = 0; e < 8; ++e)
                if (ld[e] > bv) { bv = ld[e]; bgi = tx * 8 + e; }
#pragma unroll
            for (int m = 1; m < 8; m <<= 1) {
                float ov = __shfl_xor(bv, m, 8);
                int ogi = __shfl_xor(bgi, m, 8);
                if (ov > bv || (ov == bv && ogi < bgi)) { bv = ov; bgi = ogi; }
            }
            tv[p] = bv; ti[p] = bgi;
#pragma unroll
            for (int e = 0; e < 8; ++e)        // winner clears (static idx)
                if (bgi == tx * 8 + e) ld[e] = -3.4e38f;
        }

        const int row = row0 + ty * 4 + i;

        // ambiguity: any adjacent gap in top-9 below THR -> fp64 recheck
        float mg = 3.4e38f;
#pragma unroll
        for (int p = 0; p < 8; ++p) mg = fminf(mg, tv[p] - tv[p + 1]);
        if (tx == 0 && mg < THR) {
            int idx = atomicAdd(g_cnt, 1);
            if (idx < CAP) g_rows[idx] = row;
        }

        // full softmax probs (for psum)
        const float m0 = tv[0];
        float pe[8], ps = 0.f;
#pragma unroll
        for (int e = 0; e < 8; ++e) { pe[e] = expf(acc[i][e] - m0); ps += pe[e]; }
        float s = ps;
#pragma unroll
        for (int m = 1; m < 8; m <<= 1) s += __shfl_xor(s, m, 8);
        const float inv_s = 1.f / s;
#pragma unroll
        for (int e = 0; e < 8; ++e) pcol[e] += pe[e] * inv_s;

        if (tx == 0) {  // z-loss: logaddexp(lse, log(1e-5))^2
            float lsef = m0 + logf(s);
            const float lb = -11.512925464970229f;
            float mx = fmaxf(lsef, lb), mn = fminf(lsef, lb);
            float z = mx + log1pf(expf(mn - mx));
            zsq_acc += z * z;
        }

        // gates: lane tx handles rank tx (select chain, no runtime array index)
        float mytv = tv[0]; int myti = ti[0];
#pragma unroll
        for (int p = 1; p < 8; ++p)
            if (tx == p) { mytv = tv[p]; myti = ti[p]; }
        float ge = expf(mytv - m0);
        float gs = ge;
#pragma unroll
        for (int m = 1; m < 8; m <<= 1) gs += __shfl_xor(gs, m, 8);
        const size_t base = (size_t)row * TOPK;
        out_idx[base + tx] = (float)myti;
        out_gate[base + tx] = ge / gs;
        atomicAdd(&fcnt_s[myti], 1.f);
    }

    // z-loss wave reduction -> global
#pragma unroll
    for (int off = 32; off > 0; off >>= 1) zsq_acc += __shfl_down(zsq_acc, off, 64);
    if (lane == 0) atomicAdd(g_zsum, zsq_acc);

    // probs column sums -> shared -> global
#pragma unroll
    for (int e = 0; e < 8; ++e) atomicAdd(&psum_s[tx * 8 + e], pcol[e]);
    __syncthreads();
    if (tid < NEXP) {
        atomicAdd(&g_psum[tid], psum_s[tid]);
        atomicAdd(&g_freq[tid], fcnt_s[tid]);
    }
}

// fp64 recheck of flagged rows: one wave per row, exact ordering + gates.
__global__ __launch_bounds__(256)
void fixup_kernel(const float* __restrict__ x, const float* __restrict__ W,
                  float* __restrict__ out_idx, float* __restrict__ out_gate,
                  const int* __restrict__ g_cnt, const int* __restrict__ g_rows)
{
    const int n = min(*g_cnt, CAP);
    const int lane = threadIdx.x & 63;
    const int wid = (blockIdx.x * blockDim.x + threadIdx.x) >> 6;
    const int nw = (gridDim.x * blockDim.x) >> 6;

    for (int i = wid; i < n; i += nw) {
        const int row = g_rows[i];
        const float* xr = x + (size_t)row * DDIM;
        double xl[32];
#pragma unroll
        for (int t = 0; t < 32; ++t) xl[t] = (double)xr[lane + 64 * t];

        double lg = 0.0;  // expert `lane` logit
        for (int e = 0; e < NEXP; ++e) {
            const float* wr = W + (size_t)e * DDIM;
            double p = 0.0;
#pragma unroll
            for (int t = 0; t < 32; ++t)
                p = fma(xl[t], (double)wr[lane + 64 * t], p);
#pragma unroll
            for (int m = 1; m < 64; m <<= 1) p += __shfl_xor(p, m, 64);
            if (lane == e) lg = p;
        }

        double v = lg;
        double tv[8]; int ti[8];
#pragma unroll
        for (int p = 0; p < 8; ++p) {
            double bv = v; int bgi = lane;
#pragma unroll
            for (int m = 1; m < 64; m <<= 1) {
                double ov = __shfl_xor(bv, m, 64);
                int ogi = __shfl_xor(bgi, m, 64);
                if (ov > bv || (ov == bv && ogi < bgi)) { bv = ov; bgi = ogi; }
            }
            tv[p] = bv; ti[p] = bgi;
            if (lane == bgi) v = -HUGE_VAL;
        }

        const double m0 = tv[0];
        double gs = 0.0, ge[8];
#pragma unroll
        for (int j = 0; j < 8; ++j) { ge[j] = exp(tv[j] - m0); gs += ge[j]; }
        if (lane < 8) {
            double myge = ge[0]; int myti = ti[0];
#pragma unroll
            for (int j = 1; j < 8; ++j)
                if (lane == j) { myge = ge[j]; myti = ti[j]; }
            const size_t base = (size_t)row * TOPK;
            out_idx[base + lane] = (float)myti;
            out_gate[base + lane] = (float)(myge / gs);
        }
    }
}

__global__ void finalize_kernel(const float* __restrict__ g_psum,
                                const float* __restrict__ g_freq,
                                const float* __restrict__ g_zsum,
                                float* __restrict__ out_loss)
{
    if (threadIdx.x == 0) {
        float sp = 0.f, sf = 0.f;
        for (int e = 0; e < NEXP; ++e) { sp += g_psum[e]; sf += g_freq[e]; }
        sp = fmaxf(sp, 1e-12f);
        sf = fmaxf(sf, 1e-12f);
        float sw = 0.f;
        for (int e = 0; e < NEXP; ++e) sw += (g_psum[e] / sp) * (g_freq[e] / sf);
        out_loss[0] = (float)NEXP * sw + 0.1f * (g_zsum[0] / (float)NROWS);
    }
}

extern "C" void kernel_launch(void* const* d_in, const int* in_sizes, int n_in,
                              void* d_out, int out_size, void* d_ws, size_t ws_size,
                              hipStream_t stream)
{
    const float* x = (const float*)d_in[0];
    const float* W = (const float*)d_in[1];
    float* out = (float*)d_out;
    float* out_idx  = out;                            // [65536*8] indices as float
    float* out_gate = out + (size_t)NROWS * TOPK;     // [65536*8] gates
    float* out_loss = out + (size_t)2 * NROWS * TOPK; // [1] loss

    float* acc = (float*)d_ws;        // psum[64] | freq[64] | zsum[1]
    int* cnt  = (int*)d_ws + 129;
    int* rows = (int*)d_ws + 130;
    hipMemsetAsync(d_ws, 0, 130 * sizeof(float), stream);  // psum,freq,zsum,cnt

    gate_kernel<<<NROWS / BM, NTH, 0, stream>>>(
        x, W, out_idx, out_gate, acc, acc + NEXP, acc + 2 * NEXP, cnt, rows);
    fixup_kernel<<<128, 256, 0, stream>>>(x, W, out_idx, out_gate, cnt, rows);
    finalize_kernel<<<1, 64, 0, stream>>>(acc, acc + NEXP, acc + 2 * NEXP, out_loss);
}

// Round 5
// 1011.401 us; speedup vs baseline: 4.8312x; 2.9595x over previous
//
#include <hip/hip_runtime.h>
#include <math.h>

#define NROWS 65536
#define DDIM 2048
#define NEXP 64
#define TOPK 8

constexpr int BM = 128;        // rows per block
constexpr int BK = 32;         // k-chunk
constexpr int NTH = 256;
constexpr int NT = DDIM / BK;  // 64 k-tiles
constexpr int SX = 130;        // xs stride: stores 2-way (free), float2 reads conflict-free
constexpr int SW = 66;         // ws stride: stores 2-way, float2 reads broadcast+2-way
constexpr int CAP = 8192;      // flagged-row list capacity (expect ~500)
constexpr float THR = 6e-5f;   // ambiguity gap threshold (~40 sigma of fp32 dot error)

// ws layout (words): [0..63] psum, [64..127] freq, [128] zsum, [129] cnt(int), [130..] rows
// NOTE: this toolchain caps VGPRs at 256/min_waves_per_EU:
//   (256,4) -> 64 VGPRs (round 3: 18 GB scratch), (256,2) -> 128 (round 4:
//   10 GB scratch). Kernel needs ~150 VGPRs -> min_waves must be 1.
__global__ __launch_bounds__(NTH, 1)
void gate_kernel(const float* __restrict__ x, const float* __restrict__ W,
                 float* __restrict__ out_idx, float* __restrict__ out_gate,
                 float* __restrict__ g_psum, float* __restrict__ g_freq,
                 float* __restrict__ g_zsum, int* __restrict__ g_cnt,
                 int* __restrict__ g_rows)
{
    __shared__ float xs[BK][SX];
    __shared__ float ws[BK][SW];
    __shared__ float psum_s[NEXP];
    __shared__ float fcnt_s[NEXP];

    const int tid = threadIdx.x;
    const int row0 = blockIdx.x * BM;
    const int tx = tid & 7;    // expert group: experts tx*8 .. tx*8+7
    const int ty = tid >> 3;   // row group:    rows    ty*4 .. ty*4+3
    const int lane = tid & 63;
    const int sr = tid >> 3, sc = tid & 7;  // staging coords

    if (tid < NEXP) { psum_s[tid] = 0.f; fcnt_s[tid] = 0.f; }

    float4 rx[4], rw[2];  // register prefetch buffers

    auto load_tile = [&](int k0) {
#pragma unroll
        for (int it = 0; it < 4; ++it)
            rx[it] = *reinterpret_cast<const float4*>(
                &x[(size_t)(row0 + sr + 32 * it) * DDIM + k0 + sc * 4]);
#pragma unroll
        for (int it = 0; it < 2; ++it)
            rw[it] = *reinterpret_cast<const float4*>(
                &W[(size_t)(sr + 32 * it) * DDIM + k0 + sc * 4]);
    };
    auto store_tile = [&]() {
#pragma unroll
        for (int it = 0; it < 4; ++it) {
            int r = sr + 32 * it;
            xs[sc * 4 + 0][r] = rx[it].x; xs[sc * 4 + 1][r] = rx[it].y;
            xs[sc * 4 + 2][r] = rx[it].z; xs[sc * 4 + 3][r] = rx[it].w;
        }
#pragma unroll
        for (int it = 0; it < 2; ++it) {
            int e = sr + 32 * it;
            ws[sc * 4 + 0][e] = rw[it].x; ws[sc * 4 + 1][e] = rw[it].y;
            ws[sc * 4 + 2][e] = rw[it].z; ws[sc * 4 + 3][e] = rw[it].w;
        }
    };

    float acc[4][8];
#pragma unroll
    for (int i = 0; i < 4; ++i)
#pragma unroll
        for (int e = 0; e < 8; ++e) acc[i][e] = 0.f;

    load_tile(0);
    store_tile();
    for (int t = 0; t < NT; ++t) {
        __syncthreads();                       // LDS tile t visible
        if (t + 1 < NT) load_tile((t + 1) * BK);  // prefetch next tile into regs
#pragma unroll
        for (int kk = 0; kk < BK; ++kk) {
            float a[4], b[8];
            *reinterpret_cast<float2*>(&a[0]) =
                *reinterpret_cast<const float2*>(&xs[kk][ty * 4]);
            *reinterpret_cast<float2*>(&a[2]) =
                *reinterpret_cast<const float2*>(&xs[kk][ty * 4 + 2]);
#pragma unroll
            for (int j = 0; j < 4; ++j)
                *reinterpret_cast<float2*>(&b[j * 2]) =
                    *reinterpret_cast<const float2*>(&ws[kk][tx * 8 + j * 2]);
#pragma unroll
            for (int i = 0; i < 4; ++i)
#pragma unroll
                for (int e = 0; e < 8; ++e)
                    acc[i][e] = fmaf(a[i], b[e], acc[i][e]);
        }
        __syncthreads();                       // all done reading tile t
        if (t + 1 < NT) store_tile();
    }

    // ---- epilogue: 8 lanes of a ty-group cooperate per row ----
    float zsq_acc = 0.f;
    float pcol[8];
#pragma unroll
    for (int e = 0; e < 8; ++e) pcol[e] = 0.f;

    for (int i = 0; i < 4; ++i) {
        float ld[8];
#pragma unroll
        for (int e = 0; e < 8; ++e) ld[e] = acc[i][e];

        float tv[9]; int ti[9];
#pragma unroll
        for (int p = 0; p < 9; ++p) {  // top-8 + rank-9 (for gap test)
            float bv = -3.4e38f; int bgi = 127;
#pragma unroll
            for (int e = 0; e < 8; ++e)
                if (ld[e] > bv) { bv = ld[e]; bgi = tx * 8 + e; }
#pragma unroll
            for (int m = 1; m < 8; m <<= 1) {
                float ov = __shfl_xor(bv, m, 8);
                int ogi = __shfl_xor(bgi, m, 8);
                if (ov > bv || (ov == bv && ogi < bgi)) { bv = ov; bgi = ogi; }
            }
            tv[p] = bv; ti[p] = bgi;
#pragma unroll
            for (int e = 0; e < 8; ++e)        // winner clears (static idx)
                if (bgi == tx * 8 + e) ld[e] = -3.4e38f;
        }

        const int row = row0 + ty * 4 + i;

        // ambiguity: any adjacent gap in top-9 below THR -> fp64 recheck
        float mg = 3.4e38f;
#pragma unroll
        for (int p = 0; p < 8; ++p) mg = fminf(mg, tv[p] - tv[p + 1]);
        if (tx == 0 && mg < THR) {
            int idx = atomicAdd(g_cnt, 1);
            if (idx < CAP) g_rows[idx] = row;
        }

        // full softmax probs (for psum)
        const float m0 = tv[0];
        float pe[8], ps = 0.f;
#pragma unroll
        for (int e = 0; e < 8; ++e) { pe[e] = expf(acc[i][e] - m0); ps += pe[e]; }
        float s = ps;
#pragma unroll
        for (int m = 1; m < 8; m <<= 1) s += __shfl_xor(s, m, 8);
        const float inv_s = 1.f / s;
#pragma unroll
        for (int e = 0; e < 8; ++e) pcol[e] += pe[e] * inv_s;

        if (tx == 0) {  // z-loss: logaddexp(lse, log(1e-5))^2
            float lsef = m0 + logf(s);
            const float lb = -11.512925464970229f;
            float mx = fmaxf(lsef, lb), mn = fminf(lsef, lb);
            float z = mx + log1pf(expf(mn - mx));
            zsq_acc += z * z;
        }

        // gates: lane tx handles rank tx (select chain, no runtime array index)
        float mytv = tv[0]; int myti = ti[0];
#pragma unroll
        for (int p = 1; p < 8; ++p)
            if (tx == p) { mytv = tv[p]; myti = ti[p]; }
        float ge = expf(mytv - m0);
        float gs = ge;
#pragma unroll
        for (int m = 1; m < 8; m <<= 1) gs += __shfl_xor(gs, m, 8);
        const size_t base = (size_t)row * TOPK;
        out_idx[base + tx] = (float)myti;
        out_gate[base + tx] = ge / gs;
        atomicAdd(&fcnt_s[myti], 1.f);
    }

    // z-loss wave reduction -> global
#pragma unroll
    for (int off = 32; off > 0; off >>= 1) zsq_acc += __shfl_down(zsq_acc, off, 64);
    if (lane == 0) atomicAdd(g_zsum, zsq_acc);

    // probs column sums -> shared -> global
#pragma unroll
    for (int e = 0; e < 8; ++e) atomicAdd(&psum_s[tx * 8 + e], pcol[e]);
    __syncthreads();
    if (tid < NEXP) {
        atomicAdd(&g_psum[tid], psum_s[tid]);
        atomicAdd(&g_freq[tid], fcnt_s[tid]);
    }
}

// fp64 recheck of flagged rows: one wave per row, exact ordering + gates.
__global__ __launch_bounds__(256)
void fixup_kernel(const float* __restrict__ x, const float* __restrict__ W,
                  float* __restrict__ out_idx, float* __restrict__ out_gate,
                  const int* __restrict__ g_cnt, const int* __restrict__ g_rows)
{
    const int n = min(*g_cnt, CAP);
    const int lane = threadIdx.x & 63;
    const int wid = (blockIdx.x * blockDim.x + threadIdx.x) >> 6;
    const int nw = (gridDim.x * blockDim.x) >> 6;

    for (int i = wid; i < n; i += nw) {
        const int row = g_rows[i];
        const float* xr = x + (size_t)row * DDIM;
        double xl[32];
#pragma unroll
        for (int t = 0; t < 32; ++t) xl[t] = (double)xr[lane + 64 * t];

        double lg = 0.0;  // expert `lane` logit
        for (int e = 0; e < NEXP; ++e) {
            const float* wr = W + (size_t)e * DDIM;
            double p = 0.0;
#pragma unroll
            for (int t = 0; t < 32; ++t)
                p = fma(xl[t], (double)wr[lane + 64 * t], p);
#pragma unroll
            for (int m = 1; m < 64; m <<= 1) p += __shfl_xor(p, m, 64);
            if (lane == e) lg = p;
        }

        double v = lg;
        double tv[8]; int ti[8];
#pragma unroll
        for (int p = 0; p < 8; ++p) {
            double bv = v; int bgi = lane;
#pragma unroll
            for (int m = 1; m < 64; m <<= 1) {
                double ov = __shfl_xor(bv, m, 64);
                int ogi = __shfl_xor(bgi, m, 64);
                if (ov > bv || (ov == bv && ogi < bgi)) { bv = ov; bgi = ogi; }
            }
            tv[p] = bv; ti[p] = bgi;
            if (lane == bgi) v = -HUGE_VAL;
        }

        const double m0 = tv[0];
        double gs = 0.0, ge[8];
#pragma unroll
        for (int j = 0; j < 8; ++j) { ge[j] = exp(tv[j] - m0); gs += ge[j]; }
        if (lane < 8) {
            double myge = ge[0]; int myti = ti[0];
#pragma unroll
            for (int j = 1; j < 8; ++j)
                if (lane == j) { myge = ge[j]; myti = ti[j]; }
            const size_t base = (size_t)row * TOPK;
            out_idx[base + lane] = (float)myti;
            out_gate[base + lane] = (float)(myge / gs);
        }
    }
}

__global__ void finalize_kernel(const float* __restrict__ g_psum,
                                const float* __restrict__ g_freq,
                                const float* __restrict__ g_zsum,
                                float* __restrict__ out_loss)
{
    if (threadIdx.x == 0) {
        float sp = 0.f, sf = 0.f;
        for (int e = 0; e < NEXP; ++e) { sp += g_psum[e]; sf += g_freq[e]; }
        sp = fmaxf(sp, 1e-12f);
        sf = fmaxf(sf, 1e-12f);
        float sw = 0.f;
        for (int e = 0; e < NEXP; ++e) sw += (g_psum[e] / sp) * (g_freq[e] / sf);
        out_loss[0] = (float)NEXP * sw + 0.1f * (g_zsum[0] / (float)NROWS);
    }
}

extern "C" void kernel_launch(void* const* d_in, const int* in_sizes, int n_in,
                              void* d_out, int out_size, void* d_ws, size_t ws_size,
                              hipStream_t stream)
{
    const float* x = (const float*)d_in[0];
    const float* W = (const float*)d_in[1];
    float* out = (float*)d_out;
    float* out_idx  = out;                            // [65536*8] indices as float
    float* out_gate = out + (size_t)NROWS * TOPK;     // [65536*8] gates
    float* out_loss = out + (size_t)2 * NROWS * TOPK; // [1] loss

    float* acc = (float*)d_ws;        // psum[64] | freq[64] | zsum[1]
    int* cnt  = (int*)d_ws + 129;
    int* rows = (int*)d_ws + 130;
    hipMemsetAsync(d_ws, 0, 130 * sizeof(float), stream);  // psum,freq,zsum,cnt

    gate_kernel<<<NROWS / BM, NTH, 0, stream>>>(
        x, W, out_idx, out_gate, acc, acc + NEXP, acc + 2 * NEXP, cnt, rows);
    fixup_kernel<<<128, 256, 0, stream>>>(x, W, out_idx, out_gate, cnt, rows);
    finalize_kernel<<<1, 64, 0, stream>>>(acc, acc + NEXP, acc + 2 * NEXP, out_loss);
}

// Round 6
// 882.630 us; speedup vs baseline: 5.5361x; 1.1459x over previous
//
#include <hip/hip_runtime.h>
#include <math.h>

#define NROWS 65536
#define DDIM 2048
#define NEXP 64
#define TOPK 8

constexpr int BM = 128;          // rows per block (4 waves x 32 rows)
constexpr int BK = 32;           // k per step (one mfma K)
constexpr int NTH = 256;
constexpr int NSTEP = DDIM / BK; // 64
constexpr int CAP = 8192;        // flagged-row capacity (expect ~700)
constexpr float THR = 1e-4f;     // ambiguity gap threshold (~30 sigma)

typedef short bf16x8 __attribute__((ext_vector_type(8)));
typedef float f32x4 __attribute__((ext_vector_type(4)));

__device__ inline unsigned short bfround(float f) {
    union { float f; unsigned u; } v; v.f = f;
    unsigned r = (v.u + 0x7fffu + ((v.u >> 16) & 1u)) >> 16;   // RNE
    return (unsigned short)r;
}
__device__ inline float bf2f(unsigned short h) {
    union { unsigned u; float f; } v; v.u = ((unsigned)h) << 16;
    return v.f;
}
// 8 fp32 -> bf16 hi + bf16 residual-lo fragments (all static indexing)
__device__ inline void cvt8(const float4& A, const float4& B, bf16x8& h, bf16x8& l) {
    float f[8] = {A.x, A.y, A.z, A.w, B.x, B.y, B.z, B.w};
#pragma unroll
    for (int j = 0; j < 8; ++j) {
        unsigned short hh = bfround(f[j]);
        h[j] = (short)hh;
        l[j] = (short)bfround(f[j] - bf2f(hh));
    }
}

// ws layout (words): [0..63] psum, [64..127] freq, [128] zsum, [129] cnt, [130..] rows
// VGPR lesson (r3/r4): launch_bounds min-waves caps VGPR at 256/min_waves ->
// keep min_waves=1; this kernel peaks ~150 VGPR.
__global__ __launch_bounds__(NTH, 1)
void gate_kernel(const float* __restrict__ x, const float* __restrict__ W,
                 float* __restrict__ out_idx, float* __restrict__ out_gate,
                 float* __restrict__ g_psum, float* __restrict__ g_freq,
                 float* __restrict__ g_zsum, int* __restrict__ g_cnt,
                 int* __restrict__ g_rows)
{
    // B (W^T) fragments in LDS, fragment order: [buf][hi/lo][ct][lane][8 bf16]
    // read/write addresses are lane-linear 16B slots -> conflict-free.
    __shared__ __align__(16) short Bfrag[2][2][4][64][8];
    __shared__ float psum_s[NEXP];
    __shared__ float fcnt_s[NEXP];

    const int tid = threadIdx.x;
    const int w = tid >> 6;          // wave 0..3
    const int lane = tid & 63;
    const int g = lane >> 4;         // k-subgroup (A) / row subgroup (C)
    const int c = lane & 15;         // A row offset / C col offset
    const int row0 = blockIdx.x * BM + w * 32;

    if (tid < NEXP) { psum_s[tid] = 0.f; fcnt_s[tid] = 0.f; }

    // B staging: thread t handles expert se, k-chunk skg (8 values = its frag slot)
    const int se = tid >> 2;         // 0..63
    const int skg = tid & 3;         // 0..3
    const int sct = se >> 4;
    const int slane = (se & 15) + (skg << 4);

    // A source pointers (lane's rows for rt=0/1), already offset by k-subgroup
    const float* xr0 = x + (size_t)(row0 + c) * DDIM + g * 8;
    const float* xr1 = x + (size_t)(row0 + 16 + c) * DDIM + g * 8;
    const float* wp  = W + (size_t)se * DDIM + skg * 8;

    f32x4 acc[2][4];
#pragma unroll
    for (int rt = 0; rt < 2; ++rt)
#pragma unroll
        for (int ct = 0; ct < 4; ++ct) acc[rt][ct] = (f32x4){0.f, 0.f, 0.f, 0.f};

    float4 xa[2][2], xb[2][2];

    auto stageB = [&](int k0, int buf) {
        float4 a = *reinterpret_cast<const float4*>(wp + k0);
        float4 b = *reinterpret_cast<const float4*>(wp + k0 + 4);
        bf16x8 h, l;
        cvt8(a, b, h, l);
        *reinterpret_cast<bf16x8*>(&Bfrag[buf][0][sct][slane][0]) = h;
        *reinterpret_cast<bf16x8*>(&Bfrag[buf][1][sct][slane][0]) = l;
    };

    // prologue: A(0) raw + B(0) staged
    xa[0][0] = *reinterpret_cast<const float4*>(xr0);
    xa[0][1] = *reinterpret_cast<const float4*>(xr0 + 4);
    xa[1][0] = *reinterpret_cast<const float4*>(xr1);
    xa[1][1] = *reinterpret_cast<const float4*>(xr1 + 4);
    stageB(0, 0);
    __syncthreads();

    for (int t = 0; t < NSTEP; ++t) {
        const int buf = t & 1;
        const int kn = (t + 1) * BK;
        if (t + 1 < NSTEP) {
            xb[0][0] = *reinterpret_cast<const float4*>(xr0 + kn);
            xb[0][1] = *reinterpret_cast<const float4*>(xr0 + kn + 4);
            xb[1][0] = *reinterpret_cast<const float4*>(xr1 + kn);
            xb[1][1] = *reinterpret_cast<const float4*>(xr1 + kn + 4);
            stageB(kn, buf ^ 1);
        }
        // current A -> hi/lo fragments
        bf16x8 ah[2], al[2];
        cvt8(xa[0][0], xa[0][1], ah[0], al[0]);
        cvt8(xa[1][0], xa[1][1], ah[1], al[1]);
        // B fragments (lane-linear LDS reads)
        bf16x8 bh[4], bl[4];
#pragma unroll
        for (int ct = 0; ct < 4; ++ct) {
            bh[ct] = *reinterpret_cast<const bf16x8*>(&Bfrag[buf][0][ct][lane][0]);
            bl[ct] = *reinterpret_cast<const bf16x8*>(&Bfrag[buf][1][ct][lane][0]);
        }
        // 3-term split-bf16: x*w = xh*wh + xh*wl + xl*wh (+xl*wl ~1e-6, dropped)
#pragma unroll
        for (int rt = 0; rt < 2; ++rt)
#pragma unroll
            for (int ct = 0; ct < 4; ++ct) {
                acc[rt][ct] = __builtin_amdgcn_mfma_f32_16x16x32_bf16(
                    ah[rt], bh[ct], acc[rt][ct], 0, 0, 0);
                acc[rt][ct] = __builtin_amdgcn_mfma_f32_16x16x32_bf16(
                    ah[rt], bl[ct], acc[rt][ct], 0, 0, 0);
                acc[rt][ct] = __builtin_amdgcn_mfma_f32_16x16x32_bf16(
                    al[rt], bh[ct], acc[rt][ct], 0, 0, 0);
            }
#pragma unroll
        for (int rt = 0; rt < 2; ++rt)
#pragma unroll
            for (int i = 0; i < 2; ++i) xa[rt][i] = xb[rt][i];
        __syncthreads();   // buf^1 writes done; safe for next iter's reads/writes
    }

    // ---- epilogue ----
    // C/D layout (m89): value acc[rt][ct][reg] = C[row0 + rt*16 + g*4 + reg][ct*16 + c].
    // Row R is held by the 16 lanes {g*16+c'} wait-- by lanes with same g: c'=0..15, ct=0..3.
    float pcol[4] = {0.f, 0.f, 0.f, 0.f};
    float zsq_acc = 0.f;

#pragma unroll
    for (int rt = 0; rt < 2; ++rt) {
#pragma unroll
        for (int reg = 0; reg < 4; ++reg) {
            const int row = row0 + rt * 16 + g * 4 + reg;
            float ld[4];
#pragma unroll
            for (int ct = 0; ct < 4; ++ct) ld[ct] = acc[rt][ct][reg];

            float tv[9]; int ti[9];
#pragma unroll
            for (int p = 0; p < 9; ++p) {   // top-8 + rank-9 (gap test)
                float bv = -3.4e38f; int bgi = 127;
#pragma unroll
                for (int ct = 0; ct < 4; ++ct) {
                    int e = ct * 16 + c;
                    if (ld[ct] > bv) { bv = ld[ct]; bgi = e; }
                }
#pragma unroll
                for (int m = 1; m < 16; m <<= 1) {   // width-16: stays in g-group
                    float ov = __shfl_xor(bv, m, 16);
                    int ogi = __shfl_xor(bgi, m, 16);
                    if (ov > bv || (ov == bv && ogi < bgi)) { bv = ov; bgi = ogi; }
                }
                tv[p] = bv; ti[p] = bgi;
#pragma unroll
                for (int ct = 0; ct < 4; ++ct)       // winner clears (static idx)
                    if (bgi == ct * 16 + c) ld[ct] = -3.4e38f;
            }

            // ambiguity flag -> fp64 fixup list
            float mg = 3.4e38f;
#pragma unroll
            for (int p = 0; p < 8; ++p) mg = fminf(mg, tv[p] - tv[p + 1]);
            if (c == 0 && mg < THR) {
                int idx = atomicAdd(g_cnt, 1);
                if (idx < CAP) g_rows[idx] = row;
            }

            // full softmax probs (psum) over this lane's 4 experts
            const float m0 = tv[0];
            float pe[4], ps = 0.f;
#pragma unroll
            for (int ct = 0; ct < 4; ++ct) {
                pe[ct] = expf(acc[rt][ct][reg] - m0);
                ps += pe[ct];
            }
            float s = ps;
#pragma unroll
            for (int m = 1; m < 16; m <<= 1) s += __shfl_xor(s, m, 16);
            const float inv_s = 1.f / s;
#pragma unroll
            for (int ct = 0; ct < 4; ++ct) pcol[ct] += pe[ct] * inv_s;

            if (c == 0) {   // z-loss: logaddexp(lse, log(1e-5))^2
                float lsef = m0 + logf(s);
                const float lb = -11.512925464970229f;
                float mx = fmaxf(lsef, lb), mn = fminf(lsef, lb);
                float z = mx + log1pf(expf(mn - mx));
                zsq_acc += z * z;
            }

            // top-k gates: all 16 lanes have tv/ti; lane c==p writes rank p
            float gs = 0.f;
#pragma unroll
            for (int p = 0; p < 8; ++p) gs += expf(tv[p] - m0);
            if (c < 8) {
                float mytv = tv[0]; int myti = ti[0];
#pragma unroll
                for (int p = 1; p < 8; ++p)
                    if (c == p) { mytv = tv[p]; myti = ti[p]; }
                const size_t base = (size_t)row * TOPK;
                out_idx[base + c] = (float)myti;
                out_gate[base + c] = expf(mytv - m0) / gs;
                atomicAdd(&fcnt_s[myti], 1.f);
            }
        }
    }

    // z-loss wave reduction -> global
#pragma unroll
    for (int off = 32; off > 0; off >>= 1) zsq_acc += __shfl_down(zsq_acc, off, 64);
    if (lane == 0) atomicAdd(g_zsum, zsq_acc);

    // probs column sums -> shared -> global
#pragma unroll
    for (int ct = 0; ct < 4; ++ct) atomicAdd(&psum_s[ct * 16 + c], pcol[ct]);
    __syncthreads();
    if (tid < NEXP) {
        atomicAdd(&g_psum[tid], psum_s[tid]);
        atomicAdd(&g_freq[tid], fcnt_s[tid]);
    }
}

// fp64 recheck of flagged rows: one wave per row, exact ordering + gates.
__global__ __launch_bounds__(256)
void fixup_kernel(const float* __restrict__ x, const float* __restrict__ W,
                  float* __restrict__ out_idx, float* __restrict__ out_gate,
                  const int* __restrict__ g_cnt, const int* __restrict__ g_rows)
{
    const int n = min(*g_cnt, CAP);
    const int lane = threadIdx.x & 63;
    const int wid = (blockIdx.x * blockDim.x + threadIdx.x) >> 6;
    const int nw = (gridDim.x * blockDim.x) >> 6;

    for (int i = wid; i < n; i += nw) {
        const int row = g_rows[i];
        const float* xr = x + (size_t)row * DDIM;
        double xl[32];
#pragma unroll
        for (int t = 0; t < 32; ++t) xl[t] = (double)xr[lane + 64 * t];

        double lg = 0.0;
        for (int e = 0; e < NEXP; ++e) {
            const float* wr = W + (size_t)e * DDIM;
            double p = 0.0;
#pragma unroll
            for (int t = 0; t < 32; ++t)
                p = fma(xl[t], (double)wr[lane + 64 * t], p);
#pragma unroll
            for (int m = 1; m < 64; m <<= 1) p += __shfl_xor(p, m, 64);
            if (lane == e) lg = p;
        }

        double v = lg;
        double tv[8]; int ti[8];
#pragma unroll
        for (int p = 0; p < 8; ++p) {
            double bv = v; int bgi = lane;
#pragma unroll
            for (int m = 1; m < 64; m <<= 1) {
                double ov = __shfl_xor(bv, m, 64);
                int ogi = __shfl_xor(bgi, m, 64);
                if (ov > bv || (ov == bv && ogi < bgi)) { bv = ov; bgi = ogi; }
            }
            tv[p] = bv; ti[p] = bgi;
            if (lane == bgi) v = -HUGE_VAL;
        }

        const double m0 = tv[0];
        double gs = 0.0, ge[8];
#pragma unroll
        for (int j = 0; j < 8; ++j) { ge[j] = exp(tv[j] - m0); gs += ge[j]; }
        if (lane < 8) {
            double myge = ge[0]; int myti = ti[0];
#pragma unroll
            for (int j = 1; j < 8; ++j)
                if (lane == j) { myge = ge[j]; myti = ti[j]; }
            const size_t base = (size_t)row * TOPK;
            out_idx[base + lane] = (float)myti;
            out_gate[base + lane] = (float)(myge / gs);
        }
    }
}

// wave-parallel finalize (old 1-thread version did ~128 serial global reads)
__global__ void finalize_kernel(const float* __restrict__ g_psum,
                                const float* __restrict__ g_freq,
                                const float* __restrict__ g_zsum,
                                float* __restrict__ out_loss)
{
    const int lane = threadIdx.x & 63;
    float p = g_psum[lane], f = g_freq[lane];
    float sp = p, sf = f;
#pragma unroll
    for (int m = 1; m < 64; m <<= 1) { sp += __shfl_xor(sp, m, 64); sf += __shfl_xor(sf, m, 64); }
    sp = fmaxf(sp, 1e-12f);
    sf = fmaxf(sf, 1e-12f);
    float term = (p / sp) * (f / sf);
#pragma unroll
    for (int m = 1; m < 64; m <<= 1) term += __shfl_xor(term, m, 64);
    if (lane == 0)
        out_loss[0] = (float)NEXP * term + 0.1f * (g_zsum[0] / (float)NROWS);
}

extern "C" void kernel_launch(void* const* d_in, const int* in_sizes, int n_in,
                              void* d_out, int out_size, void* d_ws, size_t ws_size,
                              hipStream_t stream)
{
    const float* x = (const float*)d_in[0];
    const float* W = (const float*)d_in[1];
    float* out = (float*)d_out;
    float* out_idx  = out;                            // [65536*8] indices as float
    float* out_gate = out + (size_t)NROWS * TOPK;     // [65536*8] gates
    float* out_loss = out + (size_t)2 * NROWS * TOPK; // [1] loss

    float* acc = (float*)d_ws;        // psum[64] | freq[64] | zsum[1]
    int* cnt  = (int*)d_ws + 129;
    int* rows = (int*)d_ws + 130;
    hipMemsetAsync(d_ws, 0, 130 * sizeof(float), stream);

    gate_kernel<<<NROWS / BM, NTH, 0, stream>>>(
        x, W, out_idx, out_gate, acc, acc + NEXP, acc + 2 * NEXP, cnt, rows);
    fixup_kernel<<<64, 256, 0, stream>>>(x, W, out_idx, out_gate, cnt, rows);
    finalize_kernel<<<1, 64, 0, stream>>>(acc, acc + NEXP, acc + 2 * NEXP, out_loss);
}

// Round 7
// 387.198 us; speedup vs baseline: 12.6197x; 2.2795x over previous
//
#include <hip/hip_runtime.h>
#include <math.h>

#define NROWS 65536
#define DDIM 2048
#define NEXP 64
#define TOPK 8

constexpr int BM = 128;          // rows per block (4 waves x 32 rows)
constexpr int BK = 32;           // k per step (one mfma K)
constexpr int NTH = 256;
constexpr int NSTEP = DDIM / BK; // 64
constexpr int CAP = 8192;        // flagged-row capacity (expect ~2300 at THR=3e-4)
constexpr float THR = 3e-4f;     // ambiguity gap threshold (split-bf16 err rms ~1.6e-5)

typedef short bf16x8 __attribute__((ext_vector_type(8)));
typedef float f32x4 __attribute__((ext_vector_type(4)));

__device__ inline unsigned short bfround(float f) {
    union { float f; unsigned u; } v; v.f = f;
    unsigned r = (v.u + 0x7fffu + ((v.u >> 16) & 1u)) >> 16;   // RNE
    return (unsigned short)r;
}
__device__ inline float bf2f(unsigned short h) {
    union { unsigned u; float f; } v; v.u = ((unsigned)h) << 16;
    return v.f;
}
// 8 fp32 -> bf16 hi + bf16 residual-lo fragments (all static indexing)
__device__ inline void cvt8(const float4& A, const float4& B, bf16x8& h, bf16x8& l) {
    float f[8] = {A.x, A.y, A.z, A.w, B.x, B.y, B.z, B.w};
#pragma unroll
    for (int j = 0; j < 8; ++j) {
        unsigned short hh = bfround(f[j]);
        h[j] = (short)hh;
        l[j] = (short)bfround(f[j] - bf2f(hh));
    }
}

// ws layout (words): [0..63] psum, [64..127] freq, [128] zsum, [129] cnt, [130..] rows
// VGPR lesson (r3/r4): launch_bounds min-waves caps VGPR at 256/min_waves ->
// keep min_waves=1; this kernel peaks ~150 VGPR.
__global__ __launch_bounds__(NTH, 1)
void gate_kernel(const float* __restrict__ x, const float* __restrict__ W,
                 float* __restrict__ out_idx, float* __restrict__ out_gate,
                 float* __restrict__ g_psum, float* __restrict__ g_freq,
                 float* __restrict__ g_zsum, int* __restrict__ g_cnt,
                 int* __restrict__ g_rows)
{
    // B (W^T) fragments in LDS, fragment order: [buf][hi/lo][ct][lane][8 bf16]
    // read/write addresses are lane-linear 16B slots -> conflict-free.
    __shared__ __align__(16) short Bfrag[2][2][4][64][8];
    __shared__ float psum_s[NEXP];
    __shared__ float fcnt_s[NEXP];

    const int tid = threadIdx.x;
    const int w = tid >> 6;          // wave 0..3
    const int lane = tid & 63;
    const int g = lane >> 4;         // k-subgroup (A) / row subgroup (C)
    const int c = lane & 15;         // A row offset / C col offset
    const int row0 = blockIdx.x * BM + w * 32;

    if (tid < NEXP) { psum_s[tid] = 0.f; fcnt_s[tid] = 0.f; }

    // B staging: thread t handles expert se, k-chunk skg (8 values = its frag slot)
    const int se = tid >> 2;         // 0..63
    const int skg = tid & 3;         // 0..3
    const int sct = se >> 4;
    const int slane = (se & 15) + (skg << 4);

    // A source pointers (lane's rows for rt=0/1), already offset by k-subgroup
    const float* xr0 = x + (size_t)(row0 + c) * DDIM + g * 8;
    const float* xr1 = x + (size_t)(row0 + 16 + c) * DDIM + g * 8;
    const float* wp  = W + (size_t)se * DDIM + skg * 8;

    f32x4 acc[2][4];
#pragma unroll
    for (int rt = 0; rt < 2; ++rt)
#pragma unroll
        for (int ct = 0; ct < 4; ++ct) acc[rt][ct] = (f32x4){0.f, 0.f, 0.f, 0.f};

    float4 xa[2][2], xb[2][2];

    auto stageB = [&](int k0, int buf) {
        float4 a = *reinterpret_cast<const float4*>(wp + k0);
        float4 b = *reinterpret_cast<const float4*>(wp + k0 + 4);
        bf16x8 h, l;
        cvt8(a, b, h, l);
        *reinterpret_cast<bf16x8*>(&Bfrag[buf][0][sct][slane][0]) = h;
        *reinterpret_cast<bf16x8*>(&Bfrag[buf][1][sct][slane][0]) = l;
    };

    // prologue: A(0) raw + B(0) staged
    xa[0][0] = *reinterpret_cast<const float4*>(xr0);
    xa[0][1] = *reinterpret_cast<const float4*>(xr0 + 4);
    xa[1][0] = *reinterpret_cast<const float4*>(xr1);
    xa[1][1] = *reinterpret_cast<const float4*>(xr1 + 4);
    stageB(0, 0);
    __syncthreads();

    for (int t = 0; t < NSTEP; ++t) {
        const int buf = t & 1;
        const int kn = (t + 1) * BK;
        if (t + 1 < NSTEP) {
            xb[0][0] = *reinterpret_cast<const float4*>(xr0 + kn);
            xb[0][1] = *reinterpret_cast<const float4*>(xr0 + kn + 4);
            xb[1][0] = *reinterpret_cast<const float4*>(xr1 + kn);
            xb[1][1] = *reinterpret_cast<const float4*>(xr1 + kn + 4);
            stageB(kn, buf ^ 1);
        }
        // current A -> hi/lo fragments
        bf16x8 ah[2], al[2];
        cvt8(xa[0][0], xa[0][1], ah[0], al[0]);
        cvt8(xa[1][0], xa[1][1], ah[1], al[1]);
        // B fragments (lane-linear LDS reads)
        bf16x8 bh[4], bl[4];
#pragma unroll
        for (int ct = 0; ct < 4; ++ct) {
            bh[ct] = *reinterpret_cast<const bf16x8*>(&Bfrag[buf][0][ct][lane][0]);
            bl[ct] = *reinterpret_cast<const bf16x8*>(&Bfrag[buf][1][ct][lane][0]);
        }
        // 3-term split-bf16: x*w = xh*wh + xh*wl + xl*wh (+xl*wl ~1e-6, dropped)
#pragma unroll
        for (int rt = 0; rt < 2; ++rt)
#pragma unroll
            for (int ct = 0; ct < 4; ++ct) {
                acc[rt][ct] = __builtin_amdgcn_mfma_f32_16x16x32_bf16(
                    ah[rt], bh[ct], acc[rt][ct], 0, 0, 0);
                acc[rt][ct] = __builtin_amdgcn_mfma_f32_16x16x32_bf16(
                    ah[rt], bl[ct], acc[rt][ct], 0, 0, 0);
                acc[rt][ct] = __builtin_amdgcn_mfma_f32_16x16x32_bf16(
                    al[rt], bh[ct], acc[rt][ct], 0, 0, 0);
            }
#pragma unroll
        for (int rt = 0; rt < 2; ++rt)
#pragma unroll
            for (int i = 0; i < 2; ++i) xa[rt][i] = xb[rt][i];
        __syncthreads();   // buf^1 writes done; safe for next iter's reads/writes
    }

    // ---- epilogue ----
    // C/D layout (m89): value acc[rt][ct][reg] = C[row0 + rt*16 + g*4 + reg][ct*16 + c].
    float pcol[4] = {0.f, 0.f, 0.f, 0.f};
    float zsq_acc = 0.f;

#pragma unroll
    for (int rt = 0; rt < 2; ++rt) {
#pragma unroll
        for (int reg = 0; reg < 4; ++reg) {
            const int row = row0 + rt * 16 + g * 4 + reg;
            float ld[4];
#pragma unroll
            for (int ct = 0; ct < 4; ++ct) ld[ct] = acc[rt][ct][reg];

            float tv[9]; int ti[9];
#pragma unroll
            for (int p = 0; p < 9; ++p) {   // top-8 + rank-9 (gap test)
                float bv = -3.4e38f; int bgi = 127;
#pragma unroll
                for (int ct = 0; ct < 4; ++ct) {
                    int e = ct * 16 + c;
                    if (ld[ct] > bv) { bv = ld[ct]; bgi = e; }
                }
#pragma unroll
                for (int m = 1; m < 16; m <<= 1) {   // width-16: stays in g-group
                    float ov = __shfl_xor(bv, m, 16);
                    int ogi = __shfl_xor(bgi, m, 16);
                    if (ov > bv || (ov == bv && ogi < bgi)) { bv = ov; bgi = ogi; }
                }
                tv[p] = bv; ti[p] = bgi;
#pragma unroll
                for (int ct = 0; ct < 4; ++ct)       // winner clears (static idx)
                    if (bgi == ct * 16 + c) ld[ct] = -3.4e38f;
            }

            // ambiguity flag -> fp64 fixup list
            float mg = 3.4e38f;
#pragma unroll
            for (int p = 0; p < 8; ++p) mg = fminf(mg, tv[p] - tv[p + 1]);
            if (c == 0 && mg < THR) {
                int idx = atomicAdd(g_cnt, 1);
                if (idx < CAP) g_rows[idx] = row;
            }

            // full softmax probs (psum) over this lane's 4 experts
            const float m0 = tv[0];
            float pe[4], ps = 0.f;
#pragma unroll
            for (int ct = 0; ct < 4; ++ct) {
                pe[ct] = expf(acc[rt][ct][reg] - m0);
                ps += pe[ct];
            }
            float s = ps;
#pragma unroll
            for (int m = 1; m < 16; m <<= 1) s += __shfl_xor(s, m, 16);
            const float inv_s = 1.f / s;
#pragma unroll
            for (int ct = 0; ct < 4; ++ct) pcol[ct] += pe[ct] * inv_s;

            if (c == 0) {   // z-loss: logaddexp(lse, log(1e-5))^2
                float lsef = m0 + logf(s);
                const float lb = -11.512925464970229f;
                float mx = fmaxf(lsef, lb), mn = fminf(lsef, lb);
                float z = mx + log1pf(expf(mn - mx));
                zsq_acc += z * z;
            }

            // top-k gates: all 16 lanes have tv/ti; lane c==p writes rank p
            float gs = 0.f;
#pragma unroll
            for (int p = 0; p < 8; ++p) gs += expf(tv[p] - m0);
            if (c < 8) {
                float mytv = tv[0]; int myti = ti[0];
#pragma unroll
                for (int p = 1; p < 8; ++p)
                    if (c == p) { mytv = tv[p]; myti = ti[p]; }
                const size_t base = (size_t)row * TOPK;
                out_idx[base + c] = (float)myti;
                out_gate[base + c] = expf(mytv - m0) / gs;
                atomicAdd(&fcnt_s[myti], 1.f);
            }
        }
    }

    // z-loss wave reduction -> global
#pragma unroll
    for (int off = 32; off > 0; off >>= 1) zsq_acc += __shfl_down(zsq_acc, off, 64);
    if (lane == 0) atomicAdd(g_zsum, zsq_acc);

    // probs column sums -> shared -> global
#pragma unroll
    for (int ct = 0; ct < 4; ++ct) atomicAdd(&psum_s[ct * 16 + c], pcol[ct]);
    __syncthreads();
    if (tid < NEXP) {
        atomicAdd(&g_psum[tid], psum_s[tid]);
        atomicAdd(&g_freq[tid], fcnt_s[tid]);
    }
}

// fp64 recheck of flagged rows, lane==expert layout: each lane computes its
// expert's full dot with 4 independent fp64 partials (ILP), x loads are
// wave-uniform (broadcast), W rows are L1/L2-resident (line reused 16x).
// Old wave-per-row/lane-per-k version was latency-serial + spilled at the
// default 64-VGPR cap -> 750 us (round-6 post-mortem).
__global__ __launch_bounds__(256, 1)
void fixup_kernel(const float* __restrict__ x, const float* __restrict__ W,
                  float* __restrict__ out_idx, float* __restrict__ out_gate,
                  const int* __restrict__ g_cnt, const int* __restrict__ g_rows)
{
    const int n = min(*g_cnt, CAP);
    const int lane = threadIdx.x & 63;
    const int wid = (blockIdx.x * blockDim.x + threadIdx.x) >> 6;
    const int nw = (gridDim.x * blockDim.x) >> 6;

    for (int i = wid; i < n; i += nw) {
        const int row = g_rows[i];
        const float* xr = x + (size_t)row * DDIM;
        const float* wr = W + (size_t)lane * DDIM;   // lane == expert
        double p0 = 0.0, p1 = 0.0, p2 = 0.0, p3 = 0.0;
#pragma unroll 4
        for (int d = 0; d < DDIM; d += 8) {
            float4 xv0 = *reinterpret_cast<const float4*>(xr + d);
            float4 xv1 = *reinterpret_cast<const float4*>(xr + d + 4);
            float4 wv0 = *reinterpret_cast<const float4*>(wr + d);
            float4 wv1 = *reinterpret_cast<const float4*>(wr + d + 4);
            p0 = fma((double)xv0.x, (double)wv0.x, p0);
            p1 = fma((double)xv0.y, (double)wv0.y, p1);
            p2 = fma((double)xv0.z, (double)wv0.z, p2);
            p3 = fma((double)xv0.w, (double)wv0.w, p3);
            p0 = fma((double)xv1.x, (double)wv1.x, p0);
            p1 = fma((double)xv1.y, (double)wv1.y, p1);
            p2 = fma((double)xv1.z, (double)wv1.z, p2);
            p3 = fma((double)xv1.w, (double)wv1.w, p3);
        }
        const double lg = (p0 + p1) + (p2 + p3);   // any fp64 order: ties need
                                                   // gap<1e-12, never happens

        double v = lg;
        double tv[8]; int ti[8];
#pragma unroll
        for (int p = 0; p < 8; ++p) {
            double bv = v; int bgi = lane;
#pragma unroll
            for (int m = 1; m < 64; m <<= 1) {
                double ov = __shfl_xor(bv, m, 64);
                int ogi = __shfl_xor(bgi, m, 64);
                if (ov > bv || (ov == bv && ogi < bgi)) { bv = ov; bgi = ogi; }
            }
            tv[p] = bv; ti[p] = bgi;
            if (lane == bgi) v = -HUGE_VAL;
        }

        const double m0 = tv[0];
        double gs = 0.0, ge[8];
#pragma unroll
        for (int j = 0; j < 8; ++j) { ge[j] = exp(tv[j] - m0); gs += ge[j]; }
        if (lane < 8) {
            double myge = ge[0]; int myti = ti[0];
#pragma unroll
            for (int j = 1; j < 8; ++j)
                if (lane == j) { myge = ge[j]; myti = ti[j]; }
            const size_t base = (size_t)row * TOPK;
            out_idx[base + lane] = (float)myti;
            out_gate[base + lane] = (float)(myge / gs);
        }
    }
}

// wave-parallel finalize
__global__ void finalize_kernel(const float* __restrict__ g_psum,
                                const float* __restrict__ g_freq,
                                const float* __restrict__ g_zsum,
                                float* __restrict__ out_loss)
{
    const int lane = threadIdx.x & 63;
    float p = g_psum[lane], f = g_freq[lane];
    float sp = p, sf = f;
#pragma unroll
    for (int m = 1; m < 64; m <<= 1) { sp += __shfl_xor(sp, m, 64); sf += __shfl_xor(sf, m, 64); }
    sp = fmaxf(sp, 1e-12f);
    sf = fmaxf(sf, 1e-12f);
    float term = (p / sp) * (f / sf);
#pragma unroll
    for (int m = 1; m < 64; m <<= 1) term += __shfl_xor(term, m, 64);
    if (lane == 0)
        out_loss[0] = (float)NEXP * term + 0.1f * (g_zsum[0] / (float)NROWS);
}

extern "C" void kernel_launch(void* const* d_in, const int* in_sizes, int n_in,
                              void* d_out, int out_size, void* d_ws, size_t ws_size,
                              hipStream_t stream)
{
    const float* x = (const float*)d_in[0];
    const float* W = (const float*)d_in[1];
    float* out = (float*)d_out;
    float* out_idx  = out;                            // [65536*8] indices as float
    float* out_gate = out + (size_t)NROWS * TOPK;     // [65536*8] gates
    float* out_loss = out + (size_t)2 * NROWS * TOPK; // [1] loss

    float* acc = (float*)d_ws;        // psum[64] | freq[64] | zsum[1]
    int* cnt  = (int*)d_ws + 129;
    int* rows = (int*)d_ws + 130;
    hipMemsetAsync(d_ws, 0, 130 * sizeof(float), stream);

    gate_kernel<<<NROWS / BM, NTH, 0, stream>>>(
        x, W, out_idx, out_gate, acc, acc + NEXP, acc + 2 * NEXP, cnt, rows);
    fixup_kernel<<<256, 256, 0, stream>>>(x, W, out_idx, out_gate, cnt, rows);
    finalize_kernel<<<1, 64, 0, stream>>>(acc, acc + NEXP, acc + 2 * NEXP, out_loss);
}

// Round 8
// 251.007 us; speedup vs baseline: 19.4669x; 1.5426x over previous
//
#include <hip/hip_runtime.h>
#include <math.h>

#define NROWS 65536
#define DDIM 2048
#define NEXP 64
#define TOPK 8

constexpr int BM = 128;          // rows per block (4 waves x 32 rows)
constexpr int BK = 32;           // k per step (one mfma K)
constexpr int NTH = 256;
constexpr int NSTEP = DDIM / BK; // 64
constexpr int CAP = 8192;        // flagged-row capacity (expect ~2300 at THR=3e-4)
constexpr float THR = 3e-4f;     // ambiguity gap threshold (split-bf16 err rms ~4e-6)

typedef short bf16x8 __attribute__((ext_vector_type(8)));
typedef float f32x4 __attribute__((ext_vector_type(4)));

__device__ inline unsigned short bfround(float f) {
    union { float f; unsigned u; } v; v.f = f;
    unsigned r = (v.u + 0x7fffu + ((v.u >> 16) & 1u)) >> 16;   // RNE
    return (unsigned short)r;
}
__device__ inline float bf2f(unsigned short h) {
    union { unsigned u; float f; } v; v.u = ((unsigned)h) << 16;
    return v.f;
}
// 8 fp32 -> bf16 hi + bf16 residual-lo fragments (all static indexing)
__device__ inline void cvt8(const float4& A, const float4& B, bf16x8& h, bf16x8& l) {
    float f[8] = {A.x, A.y, A.z, A.w, B.x, B.y, B.z, B.w};
#pragma unroll
    for (int j = 0; j < 8; ++j) {
        unsigned short hh = bfround(f[j]);
        h[j] = (short)hh;
        l[j] = (short)bfround(f[j] - bf2f(hh));
    }
}

// ws layout (words): [0..63] psum, [64..127] freq, [128] zsum, [129] cnt, [130..] rows
// VGPR lesson (r3/r4): launch_bounds min-waves caps VGPR at 256/min_waves ->
// keep min_waves=1; this kernel peaks ~240 VGPR.
__global__ __launch_bounds__(NTH, 1)
void gate_kernel(const float* __restrict__ x, const float* __restrict__ W,
                 float* __restrict__ out_idx, float* __restrict__ out_gate,
                 float* __restrict__ g_psum, float* __restrict__ g_freq,
                 float* __restrict__ g_zsum, int* __restrict__ g_cnt,
                 int* __restrict__ g_rows)
{
    // B (W^T) fragments in LDS, fragment order: [buf][hi/lo][ct][lane][8 bf16]
    // read/write addresses are lane-linear 16B slots -> conflict-free.
    __shared__ __align__(16) short Bfrag[2][2][4][64][8];
    __shared__ float psum_s[NEXP];
    __shared__ float fcnt_s[NEXP];

    const int tid = threadIdx.x;
    const int w = tid >> 6;          // wave 0..3
    const int lane = tid & 63;
    const int g = lane >> 4;         // k-subgroup (A) / row subgroup (C)
    const int c = lane & 15;         // A row offset / C col offset
    const int row0 = blockIdx.x * BM + w * 32;

    if (tid < NEXP) { psum_s[tid] = 0.f; fcnt_s[tid] = 0.f; }

    // B staging: thread t handles expert se, k-chunk skg (8 values = its frag slot)
    const int se = tid >> 2;         // 0..63
    const int skg = tid & 3;         // 0..3
    const int sct = se >> 4;
    const int slane = (se & 15) + (skg << 4);

    // A source pointers (lane's rows for rt=0/1), already offset by k-subgroup
    const float* xr0 = x + (size_t)(row0 + c) * DDIM + g * 8;
    const float* xr1 = x + (size_t)(row0 + 16 + c) * DDIM + g * 8;
    const float* wp  = W + (size_t)se * DDIM + skg * 8;

    f32x4 acc[2][4];
#pragma unroll
    for (int rt = 0; rt < 2; ++rt)
#pragma unroll
        for (int ct = 0; ct < 4; ++ct) acc[rt][ct] = (f32x4){0.f, 0.f, 0.f, 0.f};

    float4 xa[2][2], xb[2][2];

    auto stageB = [&](int k0, int buf) {
        float4 a = *reinterpret_cast<const float4*>(wp + k0);
        float4 b = *reinterpret_cast<const float4*>(wp + k0 + 4);
        bf16x8 h, l;
        cvt8(a, b, h, l);
        *reinterpret_cast<bf16x8*>(&Bfrag[buf][0][sct][slane][0]) = h;
        *reinterpret_cast<bf16x8*>(&Bfrag[buf][1][sct][slane][0]) = l;
    };

    // prologue: A(0) raw + B(0) staged
    xa[0][0] = *reinterpret_cast<const float4*>(xr0);
    xa[0][1] = *reinterpret_cast<const float4*>(xr0 + 4);
    xa[1][0] = *reinterpret_cast<const float4*>(xr1);
    xa[1][1] = *reinterpret_cast<const float4*>(xr1 + 4);
    stageB(0, 0);
    __syncthreads();

    for (int t = 0; t < NSTEP; ++t) {
        const int buf = t & 1;
        const int kn = (t + 1) * BK;
        if (t + 1 < NSTEP) {
            xb[0][0] = *reinterpret_cast<const float4*>(xr0 + kn);
            xb[0][1] = *reinterpret_cast<const float4*>(xr0 + kn + 4);
            xb[1][0] = *reinterpret_cast<const float4*>(xr1 + kn);
            xb[1][1] = *reinterpret_cast<const float4*>(xr1 + kn + 4);
            stageB(kn, buf ^ 1);
        }
        // current A -> hi/lo fragments
        bf16x8 ah[2], al[2];
        cvt8(xa[0][0], xa[0][1], ah[0], al[0]);
        cvt8(xa[1][0], xa[1][1], ah[1], al[1]);
        // B fragments (lane-linear LDS reads)
        bf16x8 bh[4], bl[4];
#pragma unroll
        for (int ct = 0; ct < 4; ++ct) {
            bh[ct] = *reinterpret_cast<const bf16x8*>(&Bfrag[buf][0][ct][lane][0]);
            bl[ct] = *reinterpret_cast<const bf16x8*>(&Bfrag[buf][1][ct][lane][0]);
        }
        // 3-term split-bf16: x*w = xh*wh + xh*wl + xl*wh (+xl*wl ~4e-6, dropped)
#pragma unroll
        for (int rt = 0; rt < 2; ++rt)
#pragma unroll
            for (int ct = 0; ct < 4; ++ct) {
                acc[rt][ct] = __builtin_amdgcn_mfma_f32_16x16x32_bf16(
                    ah[rt], bh[ct], acc[rt][ct], 0, 0, 0);
                acc[rt][ct] = __builtin_amdgcn_mfma_f32_16x16x32_bf16(
                    ah[rt], bl[ct], acc[rt][ct], 0, 0, 0);
                acc[rt][ct] = __builtin_amdgcn_mfma_f32_16x16x32_bf16(
                    al[rt], bh[ct], acc[rt][ct], 0, 0, 0);
            }
#pragma unroll
        for (int rt = 0; rt < 2; ++rt)
#pragma unroll
            for (int i = 0; i < 2; ++i) xa[rt][i] = xb[rt][i];
        __syncthreads();   // buf^1 writes done; safe for next iter's reads/writes
    }

    // ---- epilogue ----
    // C/D layout (m89): value acc[rt][ct][reg] = C[row0 + rt*16 + g*4 + reg][ct*16 + c].
    float pcol[4] = {0.f, 0.f, 0.f, 0.f};
    float zsq_acc = 0.f;

#pragma unroll
    for (int rt = 0; rt < 2; ++rt) {
#pragma unroll
        for (int reg = 0; reg < 4; ++reg) {
            const int row = row0 + rt * 16 + g * 4 + reg;
            float ld[4];
#pragma unroll
            for (int ct = 0; ct < 4; ++ct) ld[ct] = acc[rt][ct][reg];

            float tv[9]; int ti[9];
#pragma unroll
            for (int p = 0; p < 9; ++p) {   // top-8 + rank-9 (gap test)
                float bv = -3.4e38f; int bgi = 127;
#pragma unroll
                for (int ct = 0; ct < 4; ++ct) {
                    int e = ct * 16 + c;
                    if (ld[ct] > bv) { bv = ld[ct]; bgi = e; }
                }
#pragma unroll
                for (int m = 1; m < 16; m <<= 1) {   // width-16: stays in g-group
                    float ov = __shfl_xor(bv, m, 16);
                    int ogi = __shfl_xor(bgi, m, 16);
                    if (ov > bv || (ov == bv && ogi < bgi)) { bv = ov; bgi = ogi; }
                }
                tv[p] = bv; ti[p] = bgi;
#pragma unroll
                for (int ct = 0; ct < 4; ++ct)       // winner clears (static idx)
                    if (bgi == ct * 16 + c) ld[ct] = -3.4e38f;
            }

            // ambiguity flag -> fp64 fixup list
            float mg = 3.4e38f;
#pragma unroll
            for (int p = 0; p < 8; ++p) mg = fminf(mg, tv[p] - tv[p + 1]);
            if (c == 0 && mg < THR) {
                int idx = atomicAdd(g_cnt, 1);
                if (idx < CAP) g_rows[idx] = row;
            }

            // full softmax probs (psum) over this lane's 4 experts
            const float m0 = tv[0];
            float pe[4], ps = 0.f;
#pragma unroll
            for (int ct = 0; ct < 4; ++ct) {
                pe[ct] = expf(acc[rt][ct][reg] - m0);
                ps += pe[ct];
            }
            float s = ps;
#pragma unroll
            for (int m = 1; m < 16; m <<= 1) s += __shfl_xor(s, m, 16);
            const float inv_s = 1.f / s;
#pragma unroll
            for (int ct = 0; ct < 4; ++ct) pcol[ct] += pe[ct] * inv_s;

            if (c == 0) {   // z-loss: logaddexp(lse, log(1e-5))^2
                float lsef = m0 + logf(s);
                const float lb = -11.512925464970229f;
                float mx = fmaxf(lsef, lb), mn = fminf(lsef, lb);
                float z = mx + log1pf(expf(mn - mx));
                zsq_acc += z * z;
            }

            // top-k gates: all 16 lanes have tv/ti; lane c==p writes rank p
            float gs = 0.f;
#pragma unroll
            for (int p = 0; p < 8; ++p) gs += expf(tv[p] - m0);
            if (c < 8) {
                float mytv = tv[0]; int myti = ti[0];
#pragma unroll
                for (int p = 1; p < 8; ++p)
                    if (c == p) { mytv = tv[p]; myti = ti[p]; }
                const size_t base = (size_t)row * TOPK;
                out_idx[base + c] = (float)myti;
                out_gate[base + c] = expf(mytv - m0) / gs;
                atomicAdd(&fcnt_s[myti], 1.f);
            }
        }
    }

    // z-loss wave reduction -> global
#pragma unroll
    for (int off = 32; off > 0; off >>= 1) zsq_acc += __shfl_down(zsq_acc, off, 64);
    if (lane == 0) atomicAdd(g_zsum, zsq_acc);

    // probs column sums -> shared -> global
#pragma unroll
    for (int ct = 0; ct < 4; ++ct) atomicAdd(&psum_s[ct * 16 + c], pcol[ct]);
    __syncthreads();
    if (tid < NEXP) {
        atomicAdd(&g_psum[tid], psum_s[tid]);
        atomicAdd(&g_freq[tid], fcnt_s[tid]);
    }
}

// fp64 recheck, v3: BLOCK per flagged row, coalesced W reads.
// Round-7 post-mortem: v2's lane==expert gave 64 distinct cache lines per
// wave-load (8 KB lane stride) -> address-divergence-bound (~250 us).
// Now thread (e=tid>>2, q=tid&3) reads W[e][j*16+q*4 ..+3]: consecutive
// lanes hit contiguous 64B segments (16 lines/instr). x reads broadcast.
__global__ __launch_bounds__(256, 1)
void fixup_kernel(const float* __restrict__ x, const float* __restrict__ W,
                  float* __restrict__ out_idx, float* __restrict__ out_gate,
                  const int* __restrict__ g_cnt, const int* __restrict__ g_rows)
{
    const int n = min(*g_cnt, CAP);
    const int tid = threadIdx.x;
    const int e = tid >> 2;          // expert 0..63
    const int q = tid & 3;           // k-quarter phase
    __shared__ double sL[NEXP];

    for (int i = blockIdx.x; i < n; i += gridDim.x) {
        const int row = g_rows[i];
        const float* xr = x + (size_t)row * DDIM;
        const float* wr = W + (size_t)e * DDIM;

        double p0 = 0.0, p1 = 0.0, p2 = 0.0, p3 = 0.0;
#pragma unroll 4
        for (int j = 0; j < DDIM / 16; ++j) {
            const int k = j * 16 + q * 4;
            float4 wv = *reinterpret_cast<const float4*>(wr + k);
            float4 xv = *reinterpret_cast<const float4*>(xr + k);
            p0 = fma((double)xv.x, (double)wv.x, p0);
            p1 = fma((double)xv.y, (double)wv.y, p1);
            p2 = fma((double)xv.z, (double)wv.z, p2);
            p3 = fma((double)xv.w, (double)wv.w, p3);
        }
        double s = (p0 + p1) + (p2 + p3);
        s += __shfl_xor(s, 1, 4);
        s += __shfl_xor(s, 2, 4);          // all 4 lanes of the expert agree
        if (q == 0) sL[e] = s;
        __syncthreads();

        if (tid < NEXP) {                  // one wave: lane == expert
            const int lane = tid;
            double v = sL[lane];
            double tv[8]; int ti[8];
#pragma unroll
            for (int p = 0; p < 8; ++p) {
                double bv = v; int bgi = lane;
#pragma unroll
                for (int m = 1; m < 64; m <<= 1) {
                    double ov = __shfl_xor(bv, m, 64);
                    int ogi = __shfl_xor(bgi, m, 64);
                    if (ov > bv || (ov == bv && ogi < bgi)) { bv = ov; bgi = ogi; }
                }
                tv[p] = bv; ti[p] = bgi;
                if (lane == bgi) v = -HUGE_VAL;
            }

            const double m0 = tv[0];
            double gs = 0.0, ge[8];
#pragma unroll
            for (int j = 0; j < 8; ++j) { ge[j] = exp(tv[j] - m0); gs += ge[j]; }
            if (lane < 8) {
                double myge = ge[0]; int myti = ti[0];
#pragma unroll
                for (int j = 1; j < 8; ++j)
                    if (lane == j) { myge = ge[j]; myti = ti[j]; }
                const size_t base = (size_t)row * TOPK;
                out_idx[base + lane] = (float)myti;
                out_gate[base + lane] = (float)(myge / gs);
            }
        }
        __syncthreads();                   // sL safe for next row
    }
}

// wave-parallel finalize
__global__ void finalize_kernel(const float* __restrict__ g_psum,
                                const float* __restrict__ g_freq,
                                const float* __restrict__ g_zsum,
                                float* __restrict__ out_loss)
{
    const int lane = threadIdx.x & 63;
    float p = g_psum[lane], f = g_freq[lane];
    float sp = p, sf = f;
#pragma unroll
    for (int m = 1; m < 64; m <<= 1) { sp += __shfl_xor(sp, m, 64); sf += __shfl_xor(sf, m, 64); }
    sp = fmaxf(sp, 1e-12f);
    sf = fmaxf(sf, 1e-12f);
    float term = (p / sp) * (f / sf);
#pragma unroll
    for (int m = 1; m < 64; m <<= 1) term += __shfl_xor(term, m, 64);
    if (lane == 0)
        out_loss[0] = (float)NEXP * term + 0.1f * (g_zsum[0] / (float)NROWS);
}

extern "C" void kernel_launch(void* const* d_in, const int* in_sizes, int n_in,
                              void* d_out, int out_size, void* d_ws, size_t ws_size,
                              hipStream_t stream)
{
    const float* x = (const float*)d_in[0];
    const float* W = (const float*)d_in[1];
    float* out = (float*)d_out;
    float* out_idx  = out;                            // [65536*8] indices as float
    float* out_gate = out + (size_t)NROWS * TOPK;     // [65536*8] gates
    float* out_loss = out + (size_t)2 * NROWS * TOPK; // [1] loss

    float* acc = (float*)d_ws;        // psum[64] | freq[64] | zsum[1]
    int* cnt  = (int*)d_ws + 129;
    int* rows = (int*)d_ws + 130;
    hipMemsetAsync(d_ws, 0, 130 * sizeof(float), stream);

    gate_kernel<<<NROWS / BM, NTH, 0, stream>>>(
        x, W, out_idx, out_gate, acc, acc + NEXP, acc + 2 * NEXP, cnt, rows);
    fixup_kernel<<<2048, 256, 0, stream>>>(x, W, out_idx, out_gate, cnt, rows);
    finalize_kernel<<<1, 64, 0, stream>>>(acc, acc + NEXP, acc + 2 * NEXP, out_loss);
}

// Round 9
// 237.540 us; speedup vs baseline: 20.5705x; 1.0567x over previous
//
#include <hip/hip_runtime.h>
#include <math.h>

#define NROWS 65536
#define DDIM 2048
#define NEXP 64
#define TOPK 8

constexpr int BM = 128;          // rows per block (4 waves x 32 rows)
constexpr int BK = 32;           // k per step (one mfma K)
constexpr int NTH = 256;
constexpr int NSTEP = DDIM / BK; // 64
constexpr int CAP = 8192;        // flagged-row capacity (expect ~2300 at THR=3e-4)
constexpr float THR = 3e-4f;     // ambiguity gap threshold (split-bf16 err rms ~4e-6)

typedef short bf16x8 __attribute__((ext_vector_type(8)));
typedef float f32x4 __attribute__((ext_vector_type(4)));

__device__ inline unsigned short bfround(float f) {
    union { float f; unsigned u; } v; v.f = f;
    unsigned r = (v.u + 0x7fffu + ((v.u >> 16) & 1u)) >> 16;   // RNE
    return (unsigned short)r;
}
__device__ inline float bf2f(unsigned short h) {
    union { unsigned u; float f; } v; v.u = ((unsigned)h) << 16;
    return v.f;
}
// 8 fp32 -> bf16 hi + bf16 residual-lo fragments (all static indexing)
__device__ inline void cvt8(const float4& A, const float4& B, bf16x8& h, bf16x8& l) {
    float f[8] = {A.x, A.y, A.z, A.w, B.x, B.y, B.z, B.w};
#pragma unroll
    for (int j = 0; j < 8; ++j) {
        unsigned short hh = bfround(f[j]);
        h[j] = (short)hh;
        l[j] = (short)bfround(f[j] - bf2f(hh));
    }
}

// ws layout (words): [0..63] psum | [64..127] freq | [128] zsum | [129] cnt
//                    [130..130+CAP) rows | [130+CAP..) flagged-row logits (64/row)
// VGPR lesson (r3/r4): launch_bounds min-waves caps VGPR at 256/min_waves ->
// keep min_waves=1; this kernel peaks ~240 VGPR.
__global__ __launch_bounds__(NTH, 1)
void gate_kernel(const float* __restrict__ x, const float* __restrict__ W,
                 float* __restrict__ out_idx, float* __restrict__ out_gate,
                 float* __restrict__ g_psum, float* __restrict__ g_freq,
                 float* __restrict__ g_zsum, int* __restrict__ g_cnt,
                 int* __restrict__ g_rows, float* __restrict__ g_logits)
{
    // B (W^T) fragments in LDS, fragment order: [buf][hi/lo][ct][lane][8 bf16]
    // read/write addresses are lane-linear 16B slots -> conflict-free.
    __shared__ __align__(16) short Bfrag[2][2][4][64][8];
    __shared__ float psum_s[NEXP];
    __shared__ float fcnt_s[NEXP];

    const int tid = threadIdx.x;
    const int w = tid >> 6;          // wave 0..3
    const int lane = tid & 63;
    const int g = lane >> 4;         // k-subgroup (A) / row subgroup (C)
    const int c = lane & 15;         // A row offset / C col offset
    const int row0 = blockIdx.x * BM + w * 32;

    if (tid < NEXP) { psum_s[tid] = 0.f; fcnt_s[tid] = 0.f; }

    // B staging: thread t handles expert se, k-chunk skg (8 values = its frag slot)
    const int se = tid >> 2;         // 0..63
    const int skg = tid & 3;         // 0..3
    const int sct = se >> 4;
    const int slane = (se & 15) + (skg << 4);

    // A source pointers (lane's rows for rt=0/1), already offset by k-subgroup
    const float* xr0 = x + (size_t)(row0 + c) * DDIM + g * 8;
    const float* xr1 = x + (size_t)(row0 + 16 + c) * DDIM + g * 8;
    const float* wp  = W + (size_t)se * DDIM + skg * 8;

    f32x4 acc[2][4];
#pragma unroll
    for (int rt = 0; rt < 2; ++rt)
#pragma unroll
        for (int ct = 0; ct < 4; ++ct) acc[rt][ct] = (f32x4){0.f, 0.f, 0.f, 0.f};

    float4 xa[2][2], xb[2][2];

    auto stageB = [&](int k0, int buf) {
        float4 a = *reinterpret_cast<const float4*>(wp + k0);
        float4 b = *reinterpret_cast<const float4*>(wp + k0 + 4);
        bf16x8 h, l;
        cvt8(a, b, h, l);
        *reinterpret_cast<bf16x8*>(&Bfrag[buf][0][sct][slane][0]) = h;
        *reinterpret_cast<bf16x8*>(&Bfrag[buf][1][sct][slane][0]) = l;
    };

    // prologue: A(0) raw + B(0) staged
    xa[0][0] = *reinterpret_cast<const float4*>(xr0);
    xa[0][1] = *reinterpret_cast<const float4*>(xr0 + 4);
    xa[1][0] = *reinterpret_cast<const float4*>(xr1);
    xa[1][1] = *reinterpret_cast<const float4*>(xr1 + 4);
    stageB(0, 0);
    __syncthreads();

    for (int t = 0; t < NSTEP; ++t) {
        const int buf = t & 1;
        const int kn = (t + 1) * BK;
        if (t + 1 < NSTEP) {
            xb[0][0] = *reinterpret_cast<const float4*>(xr0 + kn);
            xb[0][1] = *reinterpret_cast<const float4*>(xr0 + kn + 4);
            xb[1][0] = *reinterpret_cast<const float4*>(xr1 + kn);
            xb[1][1] = *reinterpret_cast<const float4*>(xr1 + kn + 4);
            stageB(kn, buf ^ 1);
        }
        // current A -> hi/lo fragments
        bf16x8 ah[2], al[2];
        cvt8(xa[0][0], xa[0][1], ah[0], al[0]);
        cvt8(xa[1][0], xa[1][1], ah[1], al[1]);
        // B fragments (lane-linear LDS reads)
        bf16x8 bh[4], bl[4];
#pragma unroll
        for (int ct = 0; ct < 4; ++ct) {
            bh[ct] = *reinterpret_cast<const bf16x8*>(&Bfrag[buf][0][ct][lane][0]);
            bl[ct] = *reinterpret_cast<const bf16x8*>(&Bfrag[buf][1][ct][lane][0]);
        }
        // 3-term split-bf16: x*w = xh*wh + xh*wl + xl*wh (+xl*wl ~4e-6, dropped)
#pragma unroll
        for (int rt = 0; rt < 2; ++rt)
#pragma unroll
            for (int ct = 0; ct < 4; ++ct) {
                acc[rt][ct] = __builtin_amdgcn_mfma_f32_16x16x32_bf16(
                    ah[rt], bh[ct], acc[rt][ct], 0, 0, 0);
                acc[rt][ct] = __builtin_amdgcn_mfma_f32_16x16x32_bf16(
                    ah[rt], bl[ct], acc[rt][ct], 0, 0, 0);
                acc[rt][ct] = __builtin_amdgcn_mfma_f32_16x16x32_bf16(
                    al[rt], bh[ct], acc[rt][ct], 0, 0, 0);
            }
#pragma unroll
        for (int rt = 0; rt < 2; ++rt)
#pragma unroll
            for (int i = 0; i < 2; ++i) xa[rt][i] = xb[rt][i];
        __syncthreads();   // buf^1 writes done; safe for next iter's reads/writes
    }

    // ---- epilogue ----
    // C/D layout (m89): value acc[rt][ct][reg] = C[row0 + rt*16 + g*4 + reg][ct*16 + c].
    float pcol[4] = {0.f, 0.f, 0.f, 0.f};
    float zsq_acc = 0.f;

#pragma unroll
    for (int rt = 0; rt < 2; ++rt) {
#pragma unroll
        for (int reg = 0; reg < 4; ++reg) {
            const int row = row0 + rt * 16 + g * 4 + reg;
            float ld[4];
#pragma unroll
            for (int ct = 0; ct < 4; ++ct) ld[ct] = acc[rt][ct][reg];

            float tv[9]; int ti[9];
#pragma unroll
            for (int p = 0; p < 9; ++p) {   // top-8 + rank-9 (gap test)
                float bv = -3.4e38f; int bgi = 127;
#pragma unroll
                for (int ct = 0; ct < 4; ++ct) {
                    int e = ct * 16 + c;
                    if (ld[ct] > bv) { bv = ld[ct]; bgi = e; }
                }
#pragma unroll
                for (int m = 1; m < 16; m <<= 1) {   // width-16: stays in g-group
                    float ov = __shfl_xor(bv, m, 16);
                    int ogi = __shfl_xor(bgi, m, 16);
                    if (ov > bv || (ov == bv && ogi < bgi)) { bv = ov; bgi = ogi; }
                }
                tv[p] = bv; ti[p] = bgi;
#pragma unroll
                for (int ct = 0; ct < 4; ++ct)       // winner clears (static idx)
                    if (bgi == ct * 16 + c) ld[ct] = -3.4e38f;
            }

            // ambiguity flag: all 16 lanes agree on mg (tv from width-16 reduce)
            float mg = 3.4e38f;
#pragma unroll
            for (int p = 0; p < 8; ++p) mg = fminf(mg, tv[p] - tv[p + 1]);
            if (mg < THR) {
                int idx = 0;
                if (c == 0) idx = atomicAdd(g_cnt, 1);
                idx = __shfl(idx, (lane >> 4) << 4, 64);  // bcast from c==0 lane
                if (idx < CAP) {
                    if (c == 0) g_rows[idx] = row;
                    // dump this row's 64 fp32 logits for candidate pruning
#pragma unroll
                    for (int ct = 0; ct < 4; ++ct)
                        g_logits[(size_t)idx * NEXP + ct * 16 + c] = acc[rt][ct][reg];
                }
            }

            // full softmax probs (psum) over this lane's 4 experts
            const float m0 = tv[0];
            float pe[4], ps = 0.f;
#pragma unroll
            for (int ct = 0; ct < 4; ++ct) {
                pe[ct] = expf(acc[rt][ct][reg] - m0);
                ps += pe[ct];
            }
            float s = ps;
#pragma unroll
            for (int m = 1; m < 16; m <<= 1) s += __shfl_xor(s, m, 16);
            const float inv_s = 1.f / s;
#pragma unroll
            for (int ct = 0; ct < 4; ++ct) pcol[ct] += pe[ct] * inv_s;

            if (c == 0) {   // z-loss: logaddexp(lse, log(1e-5))^2
                float lsef = m0 + logf(s);
                const float lb = -11.512925464970229f;
                float mx = fmaxf(lsef, lb), mn = fminf(lsef, lb);
                float z = mx + log1pf(expf(mn - mx));
                zsq_acc += z * z;
            }

            // top-k gates: all 16 lanes have tv/ti; lane c==p writes rank p
            float gs = 0.f;
#pragma unroll
            for (int p = 0; p < 8; ++p) gs += expf(tv[p] - m0);
            if (c < 8) {
                float mytv = tv[0]; int myti = ti[0];
#pragma unroll
                for (int p = 1; p < 8; ++p)
                    if (c == p) { mytv = tv[p]; myti = ti[p]; }
                const size_t base = (size_t)row * TOPK;
                out_idx[base + c] = (float)myti;
                out_gate[base + c] = expf(mytv - m0) / gs;
                atomicAdd(&fcnt_s[myti], 1.f);
            }
        }
    }

    // z-loss wave reduction -> global
#pragma unroll
    for (int off = 32; off > 0; off >>= 1) zsq_acc += __shfl_down(zsq_acc, off, 64);
    if (lane == 0) atomicAdd(g_zsum, zsq_acc);

    // probs column sums -> shared -> global
#pragma unroll
    for (int ct = 0; ct < 4; ++ct) atomicAdd(&psum_s[ct * 16 + c], pcol[ct]);
    __syncthreads();
    if (tid < NEXP) {
        atomicAdd(&g_psum[tid], psum_s[tid]);
        atomicAdd(&g_freq[tid], fcnt_s[tid]);
    }
}

// fp64 recheck v4: candidate pruning. Round-8 post-mortem: v3 recomputed all
// 64 experts (520 KB/row) -> ~120 us. Only experts with fp32 logit >= v9-THR
// can be in the true top-8 (error <= THR/2 per side) -> ~9-10 candidates,
// ~88 KB/row, fully coalesced 512B/instr reads.
__global__ __launch_bounds__(256, 1)
void fixup_kernel(const float* __restrict__ x, const float* __restrict__ W,
                  float* __restrict__ out_idx, float* __restrict__ out_gate,
                  const int* __restrict__ g_cnt, const int* __restrict__ g_rows,
                  const float* __restrict__ g_logits)
{
    const int n = min(*g_cnt, CAP);
    const int tid = threadIdx.x;
    const int grp = tid >> 5;        // candidate group 0..7
    const int gl = tid & 31;         // lane within group
    __shared__ float sLog[NEXP];
    __shared__ double sD[16];
    __shared__ int sCand[16];
    __shared__ int sNc;

    for (int i = blockIdx.x; i < n; i += gridDim.x) {
        const int row = g_rows[i];
        if (tid < NEXP) sLog[tid] = g_logits[(size_t)i * NEXP + tid];
        if (tid == 0) sNc = 0;
        __syncthreads();

        // phase 1 (wave 0): 9th-largest fp32 logit -> candidate cutoff
        if (tid < NEXP) {
            const int lane = tid;
            const float myv = sLog[lane];
            float vv = myv;
            float v9 = 0.f;
#pragma unroll
            for (int p = 0; p < 9; ++p) {
                float bv = vv; int bgi = lane;
#pragma unroll
                for (int m = 1; m < 64; m <<= 1) {
                    float ov = __shfl_xor(bv, m, 64);
                    int ogi = __shfl_xor(bgi, m, 64);
                    if (ov > bv || (ov == bv && ogi < bgi)) { bv = ov; bgi = ogi; }
                }
                if (lane == bgi) vv = -3.4e38f;
                v9 = bv;
            }
            if (myv >= v9 - THR) {           // true top-8 subset of candidates
                int slot = atomicAdd(&sNc, 1);
                if (slot < 16) sCand[slot] = lane;   // P(>16 cands) ~ 1e-24
            }
        }
        __syncthreads();
        const int nc = min(sNc, 16);

        // phase 2: fp64 dots for candidates; 8 groups x 32 lanes, coalesced
        const float* xr = x + (size_t)row * DDIM;
        for (int cb = 0; cb < nc; cb += 8) {
            const int ci = cb + grp;
            if (ci < nc) {
                const float* wr = W + (size_t)sCand[ci] * DDIM;
                double p0 = 0.0, p1 = 0.0, p2 = 0.0, p3 = 0.0;
#pragma unroll
                for (int j = 0; j < 16; ++j) {
                    const int k = j * 128 + gl * 4;   // 32 lanes x 16B contiguous
                    float4 wv = *reinterpret_cast<const float4*>(wr + k);
                    float4 xv = *reinterpret_cast<const float4*>(xr + k);
                    p0 = fma((double)xv.x, (double)wv.x, p0);
                    p1 = fma((double)xv.y, (double)wv.y, p1);
                    p2 = fma((double)xv.z, (double)wv.z, p2);
                    p3 = fma((double)xv.w, (double)wv.w, p3);
                }
                double s = (p0 + p1) + (p2 + p3);
#pragma unroll
                for (int m = 1; m < 32; m <<= 1) s += __shfl_xor(s, m, 32);
                if (gl == 0) sD[ci] = s;
            }
        }
        __syncthreads();

        // phase 3 (wave 0): exact top-8 among candidates (fp64, id tie-break)
        if (tid < NEXP) {
            const int lane = tid;
            double v = (lane < nc) ? sD[lane] : -HUGE_VAL;
            int id = (lane < nc) ? sCand[lane] : 1000;
            double tv[8]; int ti[8];
#pragma unroll
            for (int p = 0; p < 8; ++p) {
                double bv = v; int bgi = id;
#pragma unroll
                for (int m = 1; m < 64; m <<= 1) {
                    double ov = __shfl_xor(bv, m, 64);
                    int ogi = __shfl_xor(bgi, m, 64);
                    if (ov > bv || (ov == bv && ogi < bgi)) { bv = ov; bgi = ogi; }
                }
                tv[p] = bv; ti[p] = bgi;
                if (id == bgi) v = -HUGE_VAL;
            }

            const double m0 = tv[0];
            double gs = 0.0, ge[8];
#pragma unroll
            for (int j = 0; j < 8; ++j) { ge[j] = exp(tv[j] - m0); gs += ge[j]; }
            if (lane < 8) {
                double myge = ge[0]; int myti = ti[0];
#pragma unroll
                for (int j = 1; j < 8; ++j)
                    if (lane == j) { myge = ge[j]; myti = ti[j]; }
                const size_t base = (size_t)row * TOPK;
                out_idx[base + lane] = (float)myti;
                out_gate[base + lane] = (float)(myge / gs);
            }
        }
        __syncthreads();                 // sLog/sD/sCand safe for next row
    }
}

// wave-parallel finalize
__global__ void finalize_kernel(const float* __restrict__ g_psum,
                                const float* __restrict__ g_freq,
                                const float* __restrict__ g_zsum,
                                float* __restrict__ out_loss)
{
    const int lane = threadIdx.x & 63;
    float p = g_psum[lane], f = g_freq[lane];
    float sp = p, sf = f;
#pragma unroll
    for (int m = 1; m < 64; m <<= 1) { sp += __shfl_xor(sp, m, 64); sf += __shfl_xor(sf, m, 64); }
    sp = fmaxf(sp, 1e-12f);
    sf = fmaxf(sf, 1e-12f);
    float term = (p / sp) * (f / sf);
#pragma unroll
    for (int m = 1; m < 64; m <<= 1) term += __shfl_xor(term, m, 64);
    if (lane == 0)
        out_loss[0] = (float)NEXP * term + 0.1f * (g_zsum[0] / (float)NROWS);
}

extern "C" void kernel_launch(void* const* d_in, const int* in_sizes, int n_in,
                              void* d_out, int out_size, void* d_ws, size_t ws_size,
                              hipStream_t stream)
{
    const float* x = (const float*)d_in[0];
    const float* W = (const float*)d_in[1];
    float* out = (float*)d_out;
    float* out_idx  = out;                            // [65536*8] indices as float
    float* out_gate = out + (size_t)NROWS * TOPK;     // [65536*8] gates
    float* out_loss = out + (size_t)2 * NROWS * TOPK; // [1] loss

    float* acc    = (float*)d_ws;              // psum[64] | freq[64] | zsum[1]
    int*   cnt    = (int*)d_ws + 129;
    int*   rows   = (int*)d_ws + 130;
    float* logits = (float*)d_ws + 130 + CAP;  // CAP rows x 64 fp32 logits
    hipMemsetAsync(d_ws, 0, 130 * sizeof(float), stream);

    gate_kernel<<<NROWS / BM, NTH, 0, stream>>>(
        x, W, out_idx, out_gate, acc, acc + NEXP, acc + 2 * NEXP, cnt, rows, logits);
    fixup_kernel<<<2048, 256, 0, stream>>>(x, W, out_idx, out_gate, cnt, rows, logits);
    finalize_kernel<<<1, 64, 0, stream>>>(acc, acc + NEXP, acc + 2 * NEXP, out_loss);
}